// Round 8
// baseline (21227.167 us; speedup 1.0000x reference)
//
#include <hip/hip_runtime.h>
#include <hip/hip_bf16.h>

#define BB 32
#define TT 64
#define NNODE 1024
#define EE 4096
#define NEDGE 5120        // EE + NNODE self loops
#define NHEAD 8
#define HLL 512
#define HRR 64
#define TWO_N 2048
#define KCELL 2560
#define NB 256            // persistent grid: 1 block per CU guaranteed resident

__device__ __forceinline__ float sigmoidf_(float x){ return 1.f/(1.f+expf(-x)); }
__device__ __forceinline__ float leaky(float x, float s){ return x>0.f? x : s*x; }

// ---------------- CSR by dst (deterministic), packed (src<<13 | eid) ----------------
__global__ __launch_bounds__(1024) void k_csr_off(const int* __restrict__ ei, int* __restrict__ off){
  __shared__ int deg[NNODE];
  __shared__ int scn[NNODE];
  int tid = threadIdx.x;
  deg[tid] = 1;  // self loop
  __syncthreads();
  for(int e=tid; e<EE; e+=1024) atomicAdd(&deg[ei[EE+e]], 1);
  __syncthreads();
  scn[tid] = deg[tid];
  __syncthreads();
  for(int ofs=1; ofs<1024; ofs<<=1){
    int add = (tid>=ofs)? scn[tid-ofs] : 0;
    __syncthreads();
    scn[tid] += add;
    __syncthreads();
  }
  off[tid+1] = scn[tid];
  if(tid==0) off[0] = 0;
}

__global__ __launch_bounds__(1024) void k_csr_fill(const int* __restrict__ ei,
    const int* __restrict__ off, int* __restrict__ adjp){
  __shared__ int dstb[EE];
  int tid = threadIdx.x;
  for(int e=tid; e<EE; e+=1024) dstb[e] = ei[EE+e];
  __syncthreads();
  int e = blockIdx.x*1024 + tid;
  int myd = dstb[e];
  int rank = 0;
  for(int ep=0; ep<e; ep++) rank += (dstb[ep]==myd) ? 1 : 0;
  adjp[off[myd]+rank] = (ei[e] << 13) | e;                          // real edge
  if(blockIdx.x==0) adjp[off[tid+1]-1] = (tid << 13) | (EE + tid);  // self loop last
}

// ---------------- persistent kernel (plain launch, manual grid barrier) ----------------
struct PArgs {
  const float *rain,*inflow,*lWih,*lWhh,*lbih,*lbhh,*fcW,*fcb;
  const float *g1W,*g1as,*g1ad,*g1b,*g2W,*g2as,*g2ad,*g2b;
  const float *cWih,*cWhh,*cbih,*cbhh,*lng,*lnb,*linW,*linb;
  const int *adjp,*off;
  float *pred,*lat,*att;
  float *hs,*runoff,*h1,*s1,*d1,*h2,*s2,*d2,*xf,*gbuf,*hn,*cn;
  unsigned *bar;
};

__device__ __forceinline__ void gsync(unsigned* bar){
  __syncthreads();
  if(threadIdx.x==0){
    __threadfence();                                    // release my block's writes
    unsigned gen = atomicAdd(bar+1, 0u);                // read gen BEFORE arrival
    if(atomicAdd(bar, 1u) == NB-1u){
      atomicExch(bar, 0u);                              // reset count
      __threadfence();                                  // order reset before bump
      atomicAdd(bar+1, 1u);                             // release
    } else {
      while(atomicAdd(bar+1, 0u) == gen){ __builtin_amdgcn_s_sleep(8); }
    }
    __threadfence();                                    // acquire
  }
  __syncthreads();
}

__global__ __launch_bounds__(256) void k_persist(PArgs A){
  __shared__ float SM[11392];      // 45.6 KB, stage-exclusive reuse
  const int tid = threadIdx.x;
  const int bid = blockIdx.x;

  // ===== stage 0: LSTM (bid<32) + zero hn/cn (bid 128..255) =====
  if(bid < 32){
    int b = bid, j = tid;
    float wh[HRR];
    #pragma unroll
    for(int k=0;k<HRR;k++) wh[k] = A.lWhh[j*HRR+k];
    float wi = A.lWih[j];
    float bias = A.lbih[j] + A.lbhh[j];
    float c = 0.f;
    float* h_l = SM;       // 64
    float* g_l = SM+64;    // 256
    if(j<HRR) h_l[j]=0.f;
    __syncthreads();
    for(int t=0;t<TT;t++){
      float x = A.rain[b*TT+t];
      float g = fmaf(wi,x,bias);
      #pragma unroll
      for(int k=0;k<HRR;k++) g = fmaf(wh[k], h_l[k], g);
      g_l[j]=g;
      __syncthreads();
      if(j<HRR){
        c = sigmoidf_(g_l[HRR+j])*c + sigmoidf_(g_l[j])*tanhf(g_l[2*HRR+j]);
        float h = sigmoidf_(g_l[3*HRR+j])*tanhf(c);
        h_l[j]=h;
        A.hs[(t*BB+b)*HRR+j]=h;
      }
      __syncthreads();
    }
  } else if(bid>=128){
    int i = (bid-128)*256 + tid;     // 32768 = BB*HLL*2
    if(i < BB*HLL) A.hn[i]=0.f; else A.cn[i-BB*HLL]=0.f;
  }
  gsync(A.bar);

  // ===== runoff: 2048 (t,b) pairs, 8 per block =====
  for(int i8=0;i8<8;i8++){
    int p = bid*8 + i8;              // t*32+b
    int t = p>>5, b = p&31;
    __syncthreads();
    if(tid<HRR) SM[tid] = A.hs[(t*BB+b)*HRR+tid];
    __syncthreads();
    for(int rr=0;rr<4;rr++){
      int n = rr*256 + tid;
      const float* wrow = A.fcW + n*HRR;
      float a0=0,a1=0,a2=0,a3=0;
      #pragma unroll
      for(int k=0;k<HRR;k+=4){
        float4 w=*reinterpret_cast<const float4*>(wrow+k);
        a0=fmaf(w.x,SM[k+0],a0); a1=fmaf(w.y,SM[k+1],a1);
        a2=fmaf(w.z,SM[k+2],a2); a3=fmaf(w.w,SM[k+3],a3);
      }
      float acc=(a0+a1)+(a2+a3)+A.fcb[n];
      float r=leaky(acc,0.01f);
      if(n==753) r += A.inflow[b*TT+t];
      A.runoff[(t*BB+b)*NNODE+n]=r;
      A.lat[(size_t)(b*TT+t)*NNODE+n]=r;
    }
  }
  gsync(A.bar);

  // ===== prep0 (t=0): 32768 (b,n), 128 per block =====
  if(tid < 128){
    int idx = bid*128 + tid;
    int b=idx>>10, n=idx&1023;
    float x2 = A.runoff[b*NNODE+n];
    size_t base=(size_t)b*NNODE+n;
    float hv[24];
    #pragma unroll
    for(int o=0;o<24;o++){ hv[o]=x2*A.g1W[48+o]; A.h1[base*24+o]=hv[o]; }
    #pragma unroll
    for(int hd=0;hd<NHEAD;hd++){
      float s=0,d=0;
      #pragma unroll
      for(int c2=0;c2<3;c2++){ float v2=hv[hd*3+c2]; s=fmaf(v2,A.g1as[hd*3+c2],s); d=fmaf(v2,A.g1ad[hd*3+c2],d); }
      A.s1[base*8+hd]=s; A.d1[base*8+hd]=d;
    }
  }
  gsync(A.bar);

  // ===== 64 timesteps =====
  for(int t=0;t<TT;t++){
    // ---- phase A: GAT1 edge pass + GAT2 node prep. b=bid>>3, 128 nodes/block ----
    {
      int b = bid>>3, nc = bid&7;
      size_t bbase=(size_t)b*NNODE;
      float* ss  = SM;                   // 8192
      float* x1b = SM+8192;              // 128*25 = 3200
      for(int i=tid;i<NNODE*NHEAD;i+=256) ss[i]=A.s1[bbase*8+i];
      __syncthreads();
      #pragma unroll
      for(int r=0;r<4;r++){
        int ln = r*32 + (tid>>3);
        int n = nc*128 + ln, hd = tid&7;
        int o0=A.off[n], o1=A.off[n+1];
        float dn=A.d1[(bbase+n)*8+hd];
        float m=-1e30f, den=0.f;
        for(int idx=o0;idx<o1;idx++){
          int pk=A.adjp[idx]; int s=pk>>13;
          float lg=leaky(ss[s*8+hd]+dn,0.2f);
          if(lg>m){den*=expf(m-lg);m=lg;}
          den+=expf(lg-m);
        }
        float inv=1.f/(den+1e-16f);
        float o_0=0,o_1=0,o_2=0;
        for(int idx=o0;idx<o1;idx++){
          int pk=A.adjp[idx]; int s=pk>>13, eid=pk&8191;
          float lg=leaky(ss[s*8+hd]+dn,0.2f);
          float al=expf(lg-m)*inv;
          A.att[((size_t)(t*BB+b)*NEDGE+eid)*NHEAD+hd]=al;
          const float* hr=A.h1+(bbase+s)*24+hd*3;
          o_0=fmaf(hr[0],al,o_0); o_1=fmaf(hr[1],al,o_1); o_2=fmaf(hr[2],al,o_2);
        }
        x1b[ln*25+hd*3+0]=leaky(o_0+A.g1b[hd*3+0],0.01f);
        x1b[ln*25+hd*3+1]=leaky(o_1+A.g1b[hd*3+1],0.01f);
        x1b[ln*25+hd*3+2]=leaky(o_2+A.g1b[hd*3+2],0.01f);
      }
      __syncthreads();
      #pragma unroll
      for(int r=0;r<4;r++){
        int ln=r*32+(tid>>3);
        int n=nc*128+ln, hd=tid&7;
        int oA=hd*2, oB=oA+1;
        float h0=0,h1v=0;
        #pragma unroll
        for(int k=0;k<24;k++){ float xv=x1b[ln*25+k]; h0=fmaf(xv,A.g2W[k*16+oA],h0); h1v=fmaf(xv,A.g2W[k*16+oB],h1v); }
        A.h2[(bbase+n)*16+oA]=h0; A.h2[(bbase+n)*16+oB]=h1v;
        A.s2[(bbase+n)*8+hd]=h0*A.g2as[oA]+h1v*A.g2as[oB];
        A.d2[(bbase+n)*8+hd]=h0*A.g2ad[oA]+h1v*A.g2ad[oB];
      }
    }
    gsync(A.bar);
    // ---- phase B: GAT2 edge pass -> xf ----
    {
      int b=bid>>3, nc=bid&7;
      size_t bbase=(size_t)b*NNODE;
      float* ss=SM; float* ob=SM+8192;   // 128*17 = 2176
      for(int i=tid;i<NNODE*NHEAD;i+=256) ss[i]=A.s2[bbase*8+i];
      __syncthreads();
      #pragma unroll
      for(int r=0;r<4;r++){
        int ln=r*32+(tid>>3);
        int n=nc*128+ln, hd=tid&7;
        int o0=A.off[n],o1=A.off[n+1];
        float dn=A.d2[(bbase+n)*8+hd];
        float m=-1e30f,den=0.f;
        for(int idx=o0;idx<o1;idx++){
          int pk=A.adjp[idx]; int s=pk>>13;
          float lg=leaky(ss[s*8+hd]+dn,0.2f);
          if(lg>m){den*=expf(m-lg);m=lg;}
          den+=expf(lg-m);
        }
        float inv=1.f/(den+1e-16f);
        float o_0=0,o_1=0;
        for(int idx=o0;idx<o1;idx++){
          int pk=A.adjp[idx]; int s=pk>>13;
          float lg=leaky(ss[s*8+hd]+dn,0.2f);
          float al=expf(lg-m)*inv;
          const float* hr=A.h2+(bbase+s)*16+hd*2;
          o_0=fmaf(hr[0],al,o_0); o_1=fmaf(hr[1],al,o_1);
        }
        ob[ln*17+hd*2+0]=o_0; ob[ln*17+hd*2+1]=o_1;
      }
      __syncthreads();
      #pragma unroll
      for(int r=0;r<4;r++){
        int ln=r*32+(tid>>3);
        int n=nc*128+ln, hd=tid&7;
        if(hd<2){
          float acc=0;
          #pragma unroll
          for(int k=0;k<8;k++) acc+=ob[ln*17+k*2+hd];
          float v=leaky(acc*0.125f+A.g2b[hd],0.01f);
          A.xf[b*TWO_N+n*2+hd]=v;
        }
      }
    }
    gsync(A.bar);
    // ---- phase C: cell GEMM, batch-wide (block = 8 j-rows, all 32 b, full K) ----
    {
      int jl=tid>>5, b=tid&31;
      int j=bid*8+jl;
      float a0=0,a1=0,a2=0,a3=0;
      for(int k0=0;k0<KCELL;k0+=256){
        __syncthreads();
        if(k0<TWO_N){ for(int i=0;i<32;i++) SM[tid*33+i]=A.xf[i*TWO_N+k0+tid]; }
        else        { for(int i=0;i<32;i++) SM[tid*33+i]=A.hn[i*HLL+(k0-TWO_N)+tid]; }
        __syncthreads();
        const float* wrow=(k0<TWO_N)?(A.cWih+(size_t)j*TWO_N+k0):(A.cWhh+(size_t)j*HLL+(k0-TWO_N));
        #pragma unroll 4
        for(int kk=0;kk<256;kk+=8){
          float4 w0=*reinterpret_cast<const float4*>(wrow+kk);
          float4 w1=*reinterpret_cast<const float4*>(wrow+kk+4);
          const float* xp=&SM[kk*33+b];
          a0=fmaf(w0.x,xp[0],a0);   a1=fmaf(w0.y,xp[33],a1);
          a2=fmaf(w0.z,xp[66],a2);  a3=fmaf(w0.w,xp[99],a3);
          a0=fmaf(w1.x,xp[132],a0); a1=fmaf(w1.y,xp[165],a1);
          a2=fmaf(w1.z,xp[198],a2); a3=fmaf(w1.w,xp[231],a3);
        }
      }
      A.gbuf[b*TWO_N+j]=(a0+a1)+(a2+a3);
    }
    gsync(A.bar);
    // ---- phase D: gates + LayerNorm (bid<32) ----
    if(bid<32){
      int b=bid;
      const float* r0=A.gbuf+b*TWO_N;
      float hv[2];
      #pragma unroll
      for(int hf=0;hf<2;hf++){
        int u=tid+hf*256;
        float gi=r0[u]+A.cbih[u]+A.cbhh[u];
        float gf=r0[HLL+u]+A.cbih[HLL+u]+A.cbhh[HLL+u];
        float gg=r0[2*HLL+u]+A.cbih[2*HLL+u]+A.cbhh[2*HLL+u];
        float go=r0[3*HLL+u]+A.cbih[3*HLL+u]+A.cbhh[3*HLL+u];
        float c=sigmoidf_(gf)*A.cn[b*HLL+u]+sigmoidf_(gi)*tanhf(gg);
        A.cn[b*HLL+u]=c;
        float h=sigmoidf_(go)*tanhf(c);
        hv[hf]=h;
        SM[u]=h; SM[512+u]=h*h;
      }
      __syncthreads();
      for(int s=256;s>0;s>>=1){
        if(tid<s){ SM[tid]+=SM[tid+s]; SM[512+tid]+=SM[512+tid+s]; }
        __syncthreads();
      }
      float mu=SM[0]*(1.f/HLL);
      float var=SM[512]*(1.f/HLL)-mu*mu;
      float rstd=rsqrtf(var+1e-5f);
      #pragma unroll
      for(int hf=0;hf<2;hf++){
        int u=tid+hf*256;
        A.hn[b*HLL+u]=(hv[hf]-mu)*rstd*A.lng[u]+A.lnb[u];
      }
    }
    gsync(A.bar);
    // ---- phase E: lin + softplus -> pred, fused next-step GAT1 prep ----
    {
      int jl=tid>>5, b=tid&31;
      int j=bid*8+jl;
      float a0=0,a1=0,a2=0,a3=0;
      for(int k0=0;k0<HLL;k0+=256){
        __syncthreads();
        for(int i=0;i<32;i++) SM[tid*33+i]=A.hn[i*HLL+k0+tid];
        __syncthreads();
        const float* wrow=A.linW+(size_t)j*HLL+k0;
        #pragma unroll 4
        for(int kk=0;kk<256;kk+=8){
          float4 w0=*reinterpret_cast<const float4*>(wrow+kk);
          float4 w1=*reinterpret_cast<const float4*>(wrow+kk+4);
          const float* xp=&SM[kk*33+b];
          a0=fmaf(w0.x,xp[0],a0);   a1=fmaf(w0.y,xp[33],a1);
          a2=fmaf(w0.z,xp[66],a2);  a3=fmaf(w0.w,xp[99],a3);
          a0=fmaf(w1.x,xp[132],a0); a1=fmaf(w1.y,xp[165],a1);
          a2=fmaf(w1.z,xp[198],a2); a3=fmaf(w1.w,xp[231],a3);
        }
      }
      float val=(a0+a1)+(a2+a3)+A.linb[j];
      float sp=fmaxf(val,0.f)+log1pf(expf(-fabsf(val)));
      A.pred[((size_t)b*TT+t)*TWO_N+j]=sp;
      if(t+1<TT){
        float partner=__shfl_xor(sp,32);     // jl parity swap, same b
        if((jl&1)==0){
          int n=j>>1;
          float x2=A.runoff[(size_t)(t+1)*BB*NNODE+b*NNODE+n];
          float hv2[24];
          size_t base=(size_t)b*NNODE+n;
          #pragma unroll
          for(int o=0;o<24;o++){ hv2[o]=sp*A.g1W[o]+partner*A.g1W[24+o]+x2*A.g1W[48+o]; A.h1[base*24+o]=hv2[o]; }
          #pragma unroll
          for(int hd=0;hd<NHEAD;hd++){
            float s=0,d=0;
            #pragma unroll
            for(int c2=0;c2<3;c2++){ float v2=hv2[hd*3+c2]; s=fmaf(v2,A.g1as[hd*3+c2],s); d=fmaf(v2,A.g1ad[hd*3+c2],d); }
            A.s1[base*8+hd]=s; A.d1[base*8+hd]=d;
          }
        }
      }
    }
    gsync(A.bar);
  }
}

extern "C" void kernel_launch(void* const* d_in, const int* in_sizes, int n_in,
                              void* d_out, int out_size, void* d_ws, size_t ws_size,
                              hipStream_t stream){
  const int* edge_index = (const int*)d_in[2];

  float* out  = (float*)d_out;

  float* ws = (float*)d_ws;
  float* hs     = ws;                        // 131072
  float* runoff = hs + 131072;               // 2097152
  float* h1     = runoff + 2097152;          // 786432
  float* s1     = h1 + 786432;               // 262144
  float* d1     = s1 + 262144;               // 262144
  float* h2     = d1 + 262144;               // 524288
  float* s2     = h2 + 524288;               // 262144
  float* d2     = s2 + 262144;               // 262144
  float* xfb    = d2 + 262144;               // 65536
  float* gbuf   = xfb + 65536;               // 65536
  float* hn     = gbuf + 65536;              // 16384
  float* cn     = hn + 16384;                // 16384
  int*   off    = (int*)(cn + 16384);        // 1025 (pad 1032)
  int*   adjp   = off + 1032;                // 5120
  unsigned* bar = (unsigned*)(adjp + 5120);  // 2 words
  if(ws_size < 19030056ull) return;          // diagnostic: zero output

  hipMemsetAsync(bar, 0, 8, stream);
  k_csr_off<<<1, 1024, 0, stream>>>(edge_index, off);
  k_csr_fill<<<4, 1024, 0, stream>>>(edge_index, off, adjp);

  PArgs a;
  a.rain  = (const float*)d_in[0];  a.inflow= (const float*)d_in[1];
  a.lWih  = (const float*)d_in[3];  a.lWhh  = (const float*)d_in[4];
  a.lbih  = (const float*)d_in[5];  a.lbhh  = (const float*)d_in[6];
  a.fcW   = (const float*)d_in[7];  a.fcb   = (const float*)d_in[8];
  a.g1W   = (const float*)d_in[9];  a.g1as  = (const float*)d_in[10];
  a.g1ad  = (const float*)d_in[11]; a.g1b   = (const float*)d_in[12];
  a.g2W   = (const float*)d_in[13]; a.g2as  = (const float*)d_in[14];
  a.g2ad  = (const float*)d_in[15]; a.g2b   = (const float*)d_in[16];
  a.cWih  = (const float*)d_in[17]; a.cWhh  = (const float*)d_in[18];
  a.cbih  = (const float*)d_in[19]; a.cbhh  = (const float*)d_in[20];
  a.lng   = (const float*)d_in[21]; a.lnb   = (const float*)d_in[22];
  a.linW  = (const float*)d_in[23]; a.linb  = (const float*)d_in[24];
  a.adjp  = adjp; a.off = off;
  a.pred  = out;                        // (B,T,2N)
  a.lat   = out + (size_t)4194304;      // (B,T,N,1)
  a.att   = out + (size_t)6291456;      // (T,B,5120,8)
  a.hs=hs; a.runoff=runoff; a.h1=h1; a.s1=s1; a.d1=d1;
  a.h2=h2; a.s2=s2; a.d2=d2; a.xf=xfb; a.gbuf=gbuf;
  a.hn=hn; a.cn=cn; a.bar=bar;

  k_persist<<<NB, 256, 0, stream>>>(a);
}

// Round 11
// 16737.888 us; speedup vs baseline: 1.2682x; 1.2682x over previous
//
#include <hip/hip_runtime.h>
#include <hip/hip_bf16.h>

#define BB 32
#define TT 64
#define NNODE 1024
#define EE 4096
#define NEDGE 5120        // EE + NNODE self loops
#define NHEAD 8
#define HLL 512
#define HRR 64
#define TWO_N 2048
#define KCELL 2560
#define NB 256            // persistent grid: 1 block per CU — residency PROVEN in R8

__device__ __forceinline__ float sigmoidf_(float x){ return 1.f/(1.f+expf(-x)); }
__device__ __forceinline__ float leaky(float x, float s){ return x>0.f? x : s*x; }

// ---------------- CSR by dst (deterministic), packed (src<<13 | eid) ----------------
__global__ __launch_bounds__(1024) void k_csr_off(const int* __restrict__ ei, int* __restrict__ off){
  __shared__ int deg[NNODE];
  __shared__ int scn[NNODE];
  int tid = threadIdx.x;
  deg[tid] = 1;  // self loop
  __syncthreads();
  for(int e=tid; e<EE; e+=1024) atomicAdd(&deg[ei[EE+e]], 1);
  __syncthreads();
  scn[tid] = deg[tid];
  __syncthreads();
  for(int ofs=1; ofs<1024; ofs<<=1){
    int add = (tid>=ofs)? scn[tid-ofs] : 0;
    __syncthreads();
    scn[tid] += add;
    __syncthreads();
  }
  off[tid+1] = scn[tid];
  if(tid==0) off[0] = 0;
}

__global__ __launch_bounds__(1024) void k_csr_fill(const int* __restrict__ ei,
    const int* __restrict__ off, int* __restrict__ adjp){
  __shared__ int dstb[EE];
  int tid = threadIdx.x;
  for(int e=tid; e<EE; e+=1024) dstb[e] = ei[EE+e];
  __syncthreads();
  int e = blockIdx.x*1024 + tid;
  int myd = dstb[e];
  int rank = 0;
  for(int ep=0; ep<e; ep++) rank += (dstb[ep]==myd) ? 1 : 0;
  adjp[off[myd]+rank] = (ei[e] << 13) | e;                          // real edge
  if(blockIdx.x==0) adjp[off[tid+1]-1] = (tid << 13) | (EE + tid);  // self loop last
}

// ---------------- persistent kernel (plain launch, monotonic tree barrier) ----------------
// bar layout, one unsigned per 64B line (16-word stride):
//   [l*16]        l=0..31  : leaf-gen   (spun on; cumulative barrier count)
//   [(32+l)*16]   l=0..31  : leaf-arrive (cumulative)
//   [(64+m)*16]   m=0..3   : mid-arrive  (cumulative)
//   [68*16]                : root-arrive (cumulative)
//   [(69+b)*16]   b=0..31  : batch-gen   (cumulative)
//   [(101+b)*16]  b=0..31  : batch-arrive(cumulative)
// ALL mutation via default atomicAdd (RMW at LLC) — no stores, no resets (R9/R10 lesson).
struct PArgs {
  const float *rain,*inflow,*lWih,*lWhh,*lbih,*lbhh,*fcW,*fcb;
  const float *g1W,*g1as,*g1ad,*g1b,*g2W,*g2as,*g2ad,*g2b;
  const float *cWih,*cWhh,*cbih,*cbhh,*lng,*lnb,*linW,*linb;
  const int *adjp,*off;
  float *pred,*lat,*att;
  float *hs,*runoff,*h1,*s1,*d1,*h2,*s2,*d2,*xf,*gbuf,*hn,*cn;
  unsigned *bar;
};

__device__ __forceinline__ void gsync(unsigned* bar, unsigned kk){
  __syncthreads();
  if(threadIdx.x==0){
    __threadfence();                                        // release
    unsigned leaf = blockIdx.x & 31u;
    unsigned* LG = bar + leaf*16;
    if((atomicAdd(bar + (32u+leaf)*16, 1u) & 7u) == 7u){    // 8 blocks per leaf
      unsigned mid = leaf & 3u;
      if((atomicAdd(bar + (64u+mid)*16, 1u) & 7u) == 7u){   // 8 leaves per mid
        if((atomicAdd(bar + 68u*16, 1u) & 3u) == 3u){       // 4 mids
          #pragma unroll
          for(int l=0;l<32;l++) atomicAdd(bar + l*16, 1u);  // fan-out release
        }
      }
    }
    while(atomicAdd(LG, 0u) < kk){ __builtin_amdgcn_s_sleep(8); }
    __threadfence();                                        // acquire
  }
  __syncthreads();
}

__device__ __forceinline__ void bsync(unsigned* bar, int b, unsigned kk){
  __syncthreads();
  if(threadIdx.x==0){
    __threadfence();
    unsigned* BG = bar + (69u+b)*16;
    if((atomicAdd(bar + (101u+b)*16, 1u) & 7u) == 7u)       // 8 blocks per batch
      atomicAdd(BG, 1u);
    while(atomicAdd(BG, 0u) < kk){ __builtin_amdgcn_s_sleep(8); }
    __threadfence();
  }
  __syncthreads();
}

__global__ __launch_bounds__(256) void k_persist(PArgs A){
  __shared__ float SM[11392];      // 45.6 KB, stage-exclusive reuse
  const int tid = threadIdx.x;
  const int bid = blockIdx.x;

  // ===== stage 0: LSTM (bid<32) + zero hn/cn (bid 128..255) =====
  if(bid < 32){
    int b = bid, j = tid;
    float wh[HRR];
    #pragma unroll
    for(int k=0;k<HRR;k++) wh[k] = A.lWhh[j*HRR+k];
    float wi = A.lWih[j];
    float bias = A.lbih[j] + A.lbhh[j];
    float c = 0.f;
    float* h_l = SM;       // 64
    float* g_l = SM+64;    // 256
    if(j<HRR) h_l[j]=0.f;
    __syncthreads();
    for(int t=0;t<TT;t++){
      float x = A.rain[b*TT+t];
      float g = fmaf(wi,x,bias);
      #pragma unroll
      for(int k=0;k<HRR;k++) g = fmaf(wh[k], h_l[k], g);
      g_l[j]=g;
      __syncthreads();
      if(j<HRR){
        c = sigmoidf_(g_l[HRR+j])*c + sigmoidf_(g_l[j])*tanhf(g_l[2*HRR+j]);
        float h = sigmoidf_(g_l[3*HRR+j])*tanhf(c);
        h_l[j]=h;
        A.hs[(t*BB+b)*HRR+j]=h;
      }
      __syncthreads();
    }
  } else if(bid>=128){
    int i = (bid-128)*256 + tid;     // 32768 = BB*HLL*2
    if(i < BB*HLL) A.hn[i]=0.f; else A.cn[i-BB*HLL]=0.f;
  }
  gsync(A.bar, 1u);

  // ===== runoff: 2048 (t,b) pairs, 8 per block =====
  for(int i8=0;i8<8;i8++){
    int p = bid*8 + i8;              // t*32+b
    int t = p>>5, b = p&31;
    __syncthreads();
    if(tid<HRR) SM[tid] = A.hs[(t*BB+b)*HRR+tid];
    __syncthreads();
    for(int rr=0;rr<4;rr++){
      int n = rr*256 + tid;
      const float* wrow = A.fcW + n*HRR;
      float a0=0,a1=0,a2=0,a3=0;
      #pragma unroll
      for(int k=0;k<HRR;k+=4){
        float4 w=*reinterpret_cast<const float4*>(wrow+k);
        a0=fmaf(w.x,SM[k+0],a0); a1=fmaf(w.y,SM[k+1],a1);
        a2=fmaf(w.z,SM[k+2],a2); a3=fmaf(w.w,SM[k+3],a3);
      }
      float acc=(a0+a1)+(a2+a3)+A.fcb[n];
      float r=leaky(acc,0.01f);
      if(n==753) r += A.inflow[b*TT+t];
      A.runoff[(t*BB+b)*NNODE+n]=r;
      A.lat[(size_t)(b*TT+t)*NNODE+n]=r;
    }
  }
  gsync(A.bar, 2u);

  // ===== prep0 (t=0): 32768 (b,n), 128 per block =====
  if(tid < 128){
    int idx = bid*128 + tid;
    int b=idx>>10, n=idx&1023;
    float x2 = A.runoff[b*NNODE+n];
    size_t base=(size_t)b*NNODE+n;
    float hv[24];
    #pragma unroll
    for(int o=0;o<24;o++){ hv[o]=x2*A.g1W[48+o]; A.h1[base*24+o]=hv[o]; }
    #pragma unroll
    for(int hd=0;hd<NHEAD;hd++){
      float s=0,d=0;
      #pragma unroll
      for(int c2=0;c2<3;c2++){ float v2=hv[hd*3+c2]; s=fmaf(v2,A.g1as[hd*3+c2],s); d=fmaf(v2,A.g1ad[hd*3+c2],d); }
      A.s1[base*8+hd]=s; A.d1[base*8+hd]=d;
    }
  }
  gsync(A.bar, 3u);

  // ===== 64 timesteps =====
  for(int t=0;t<TT;t++){
    // ---- phase A: GAT1 edge pass + GAT2 node prep. b=bid>>3, 128 nodes/block ----
    {
      int b = bid>>3, nc = bid&7;
      size_t bbase=(size_t)b*NNODE;
      float* ss  = SM;                   // 8192
      float* x1b = SM+8192;              // 128*25 = 3200
      for(int i=tid;i<NNODE*NHEAD;i+=256) ss[i]=A.s1[bbase*8+i];
      __syncthreads();
      #pragma unroll
      for(int r=0;r<4;r++){
        int ln = r*32 + (tid>>3);
        int n = nc*128 + ln, hd = tid&7;
        int o0=A.off[n], o1=A.off[n+1];
        float dn=A.d1[(bbase+n)*8+hd];
        float m=-1e30f, den=0.f;
        for(int idx=o0;idx<o1;idx++){
          int pk=A.adjp[idx]; int s=pk>>13;
          float lg=leaky(ss[s*8+hd]+dn,0.2f);
          if(lg>m){den*=expf(m-lg);m=lg;}
          den+=expf(lg-m);
        }
        float inv=1.f/(den+1e-16f);
        float o_0=0,o_1=0,o_2=0;
        for(int idx=o0;idx<o1;idx++){
          int pk=A.adjp[idx]; int s=pk>>13, eid=pk&8191;
          float lg=leaky(ss[s*8+hd]+dn,0.2f);
          float al=expf(lg-m)*inv;
          A.att[((size_t)(t*BB+b)*NEDGE+eid)*NHEAD+hd]=al;
          const float* hr=A.h1+(bbase+s)*24+hd*3;
          o_0=fmaf(hr[0],al,o_0); o_1=fmaf(hr[1],al,o_1); o_2=fmaf(hr[2],al,o_2);
        }
        x1b[ln*25+hd*3+0]=leaky(o_0+A.g1b[hd*3+0],0.01f);
        x1b[ln*25+hd*3+1]=leaky(o_1+A.g1b[hd*3+1],0.01f);
        x1b[ln*25+hd*3+2]=leaky(o_2+A.g1b[hd*3+2],0.01f);
      }
      __syncthreads();
      #pragma unroll
      for(int r=0;r<4;r++){
        int ln=r*32+(tid>>3);
        int n=nc*128+ln, hd=tid&7;
        int oA=hd*2, oB=oA+1;
        float h0=0,h1v=0;
        #pragma unroll
        for(int k=0;k<24;k++){ float xv=x1b[ln*25+k]; h0=fmaf(xv,A.g2W[k*16+oA],h0); h1v=fmaf(xv,A.g2W[k*16+oB],h1v); }
        A.h2[(bbase+n)*16+oA]=h0; A.h2[(bbase+n)*16+oB]=h1v;
        A.s2[(bbase+n)*8+hd]=h0*A.g2as[oA]+h1v*A.g2as[oB];
        A.d2[(bbase+n)*8+hd]=h0*A.g2ad[oA]+h1v*A.g2ad[oB];
      }
    }
    bsync(A.bar, bid>>3, (unsigned)(t+1));   // per-batch: GAT2 reads only own batch
    // ---- phase B: GAT2 edge pass -> xf ----
    {
      int b=bid>>3, nc=bid&7;
      size_t bbase=(size_t)b*NNODE;
      float* ss=SM; float* ob=SM+8192;   // 128*17 = 2176
      for(int i=tid;i<NNODE*NHEAD;i+=256) ss[i]=A.s2[bbase*8+i];
      __syncthreads();
      #pragma unroll
      for(int r=0;r<4;r++){
        int ln=r*32+(tid>>3);
        int n=nc*128+ln, hd=tid&7;
        int o0=A.off[n],o1=A.off[n+1];
        float dn=A.d2[(bbase+n)*8+hd];
        float m=-1e30f,den=0.f;
        for(int idx=o0;idx<o1;idx++){
          int pk=A.adjp[idx]; int s=pk>>13;
          float lg=leaky(ss[s*8+hd]+dn,0.2f);
          if(lg>m){den*=expf(m-lg);m=lg;}
          den+=expf(lg-m);
        }
        float inv=1.f/(den+1e-16f);
        float o_0=0,o_1=0;
        for(int idx=o0;idx<o1;idx++){
          int pk=A.adjp[idx]; int s=pk>>13;
          float lg=leaky(ss[s*8+hd]+dn,0.2f);
          float al=expf(lg-m)*inv;
          const float* hr=A.h2+(bbase+s)*16+hd*2;
          o_0=fmaf(hr[0],al,o_0); o_1=fmaf(hr[1],al,o_1);
        }
        ob[ln*17+hd*2+0]=o_0; ob[ln*17+hd*2+1]=o_1;
      }
      __syncthreads();
      #pragma unroll
      for(int r=0;r<4;r++){
        int ln=r*32+(tid>>3);
        int n=nc*128+ln, hd=tid&7;
        if(hd<2){
          float acc=0;
          #pragma unroll
          for(int k=0;k<8;k++) acc+=ob[ln*17+k*2+hd];
          float v=leaky(acc*0.125f+A.g2b[hd],0.01f);
          A.xf[b*TWO_N+n*2+hd]=v;
        }
      }
    }
    gsync(A.bar, (unsigned)(4+4*t));
    // ---- phase C: cell GEMM, batch-wide (block = 8 j-rows, all 32 b, full K) ----
    {
      int jl=tid>>5, b=tid&31;
      int j=bid*8+jl;
      float a0=0,a1=0,a2=0,a3=0;
      for(int k0=0;k0<KCELL;k0+=256){
        __syncthreads();
        if(k0<TWO_N){ for(int i=0;i<32;i++) SM[tid*33+i]=A.xf[i*TWO_N+k0+tid]; }
        else        { for(int i=0;i<32;i++) SM[tid*33+i]=A.hn[i*HLL+(k0-TWO_N)+tid]; }
        __syncthreads();
        const float* wrow=(k0<TWO_N)?(A.cWih+(size_t)j*TWO_N+k0):(A.cWhh+(size_t)j*HLL+(k0-TWO_N));
        #pragma unroll 4
        for(int kk=0;kk<256;kk+=8){
          float4 w0=*reinterpret_cast<const float4*>(wrow+kk);
          float4 w1=*reinterpret_cast<const float4*>(wrow+kk+4);
          const float* xp=&SM[kk*33+b];
          a0=fmaf(w0.x,xp[0],a0);   a1=fmaf(w0.y,xp[33],a1);
          a2=fmaf(w0.z,xp[66],a2);  a3=fmaf(w0.w,xp[99],a3);
          a0=fmaf(w1.x,xp[132],a0); a1=fmaf(w1.y,xp[165],a1);
          a2=fmaf(w1.z,xp[198],a2); a3=fmaf(w1.w,xp[231],a3);
        }
      }
      A.gbuf[b*TWO_N+j]=(a0+a1)+(a2+a3);
    }
    gsync(A.bar, (unsigned)(5+4*t));
    // ---- phase D: gates + LayerNorm (bid<32) ----
    if(bid<32){
      int b=bid;
      const float* r0=A.gbuf+b*TWO_N;
      float hv[2];
      #pragma unroll
      for(int hf=0;hf<2;hf++){
        int u=tid+hf*256;
        float gi=r0[u]+A.cbih[u]+A.cbhh[u];
        float gf=r0[HLL+u]+A.cbih[HLL+u]+A.cbhh[HLL+u];
        float gg=r0[2*HLL+u]+A.cbih[2*HLL+u]+A.cbhh[2*HLL+u];
        float go=r0[3*HLL+u]+A.cbih[3*HLL+u]+A.cbhh[3*HLL+u];
        float c=sigmoidf_(gf)*A.cn[b*HLL+u]+sigmoidf_(gi)*tanhf(gg);
        A.cn[b*HLL+u]=c;
        float h=sigmoidf_(go)*tanhf(c);
        hv[hf]=h;
        SM[u]=h; SM[512+u]=h*h;
      }
      __syncthreads();
      for(int s=256;s>0;s>>=1){
        if(tid<s){ SM[tid]+=SM[tid+s]; SM[512+tid]+=SM[512+tid+s]; }
        __syncthreads();
      }
      float mu=SM[0]*(1.f/HLL);
      float var=SM[512]*(1.f/HLL)-mu*mu;
      float rstd=rsqrtf(var+1e-5f);
      #pragma unroll
      for(int hf=0;hf<2;hf++){
        int u=tid+hf*256;
        A.hn[b*HLL+u]=(hv[hf]-mu)*rstd*A.lng[u]+A.lnb[u];
      }
    }
    gsync(A.bar, (unsigned)(6+4*t));
    // ---- phase E: lin + softplus -> pred, fused next-step GAT1 prep ----
    {
      int jl=tid>>5, b=tid&31;
      int j=bid*8+jl;
      float a0=0,a1=0,a2=0,a3=0;
      for(int k0=0;k0<HLL;k0+=256){
        __syncthreads();
        for(int i=0;i<32;i++) SM[tid*33+i]=A.hn[i*HLL+k0+tid];
        __syncthreads();
        const float* wrow=A.linW+(size_t)j*HLL+k0;
        #pragma unroll 4
        for(int kk=0;kk<256;kk+=8){
          float4 w0=*reinterpret_cast<const float4*>(wrow+kk);
          float4 w1=*reinterpret_cast<const float4*>(wrow+kk+4);
          const float* xp=&SM[kk*33+b];
          a0=fmaf(w0.x,xp[0],a0);   a1=fmaf(w0.y,xp[33],a1);
          a2=fmaf(w0.z,xp[66],a2);  a3=fmaf(w0.w,xp[99],a3);
          a0=fmaf(w1.x,xp[132],a0); a1=fmaf(w1.y,xp[165],a1);
          a2=fmaf(w1.z,xp[198],a2); a3=fmaf(w1.w,xp[231],a3);
        }
      }
      float val=(a0+a1)+(a2+a3)+A.linb[j];
      float sp=fmaxf(val,0.f)+log1pf(expf(-fabsf(val)));
      A.pred[((size_t)b*TT+t)*TWO_N+j]=sp;
      if(t+1<TT){
        float partner=__shfl_xor(sp,32);     // jl parity swap, same b
        if((jl&1)==0){
          int n=j>>1;
          float x2=A.runoff[(size_t)(t+1)*BB*NNODE+b*NNODE+n];
          float hv2[24];
          size_t base=(size_t)b*NNODE+n;
          #pragma unroll
          for(int o=0;o<24;o++){ hv2[o]=sp*A.g1W[o]+partner*A.g1W[24+o]+x2*A.g1W[48+o]; A.h1[base*24+o]=hv2[o]; }
          #pragma unroll
          for(int hd=0;hd<NHEAD;hd++){
            float s=0,d=0;
            #pragma unroll
            for(int c2=0;c2<3;c2++){ float v2=hv2[hd*3+c2]; s=fmaf(v2,A.g1as[hd*3+c2],s); d=fmaf(v2,A.g1ad[hd*3+c2],d); }
            A.s1[base*8+hd]=s; A.d1[base*8+hd]=d;
          }
        }
      }
    }
    gsync(A.bar, (unsigned)(7+4*t));
  }
}

extern "C" void kernel_launch(void* const* d_in, const int* in_sizes, int n_in,
                              void* d_out, int out_size, void* d_ws, size_t ws_size,
                              hipStream_t stream){
  const int* edge_index = (const int*)d_in[2];

  float* out  = (float*)d_out;

  float* ws = (float*)d_ws;
  float* hs     = ws;                        // 131072
  float* runoff = hs + 131072;               // 2097152
  float* h1     = runoff + 2097152;          // 786432
  float* s1     = h1 + 786432;               // 262144
  float* d1     = s1 + 262144;               // 262144
  float* h2     = d1 + 262144;               // 524288
  float* s2     = h2 + 524288;               // 262144
  float* d2     = s2 + 262144;               // 262144
  float* xfb    = d2 + 262144;               // 65536
  float* gbuf   = xfb + 65536;               // 65536
  float* hn     = gbuf + 65536;              // 16384
  float* cn     = hn + 16384;                // 16384
  int*   off    = (int*)(cn + 16384);        // 1025 (pad 1032)
  int*   adjp   = off + 1032;                // 5120
  unsigned* bar = (unsigned*)(((uintptr_t)(adjp + 5120) + 255) & ~(uintptr_t)255);  // 133 lines
  if(ws_size < 19038784ull) return;          // diagnostic: zero output

  hipMemsetAsync(bar, 0, 133*64, stream);
  k_csr_off<<<1, 1024, 0, stream>>>(edge_index, off);
  k_csr_fill<<<4, 1024, 0, stream>>>(edge_index, off, adjp);

  PArgs a;
  a.rain  = (const float*)d_in[0];  a.inflow= (const float*)d_in[1];
  a.lWih  = (const float*)d_in[3];  a.lWhh  = (const float*)d_in[4];
  a.lbih  = (const float*)d_in[5];  a.lbhh  = (const float*)d_in[6];
  a.fcW   = (const float*)d_in[7];  a.fcb   = (const float*)d_in[8];
  a.g1W   = (const float*)d_in[9];  a.g1as  = (const float*)d_in[10];
  a.g1ad  = (const float*)d_in[11]; a.g1b   = (const float*)d_in[12];
  a.g2W   = (const float*)d_in[13]; a.g2as  = (const float*)d_in[14];
  a.g2ad  = (const float*)d_in[15]; a.g2b   = (const float*)d_in[16];
  a.cWih  = (const float*)d_in[17]; a.cWhh  = (const float*)d_in[18];
  a.cbih  = (const float*)d_in[19]; a.cbhh  = (const float*)d_in[20];
  a.lng   = (const float*)d_in[21]; a.lnb   = (const float*)d_in[22];
  a.linW  = (const float*)d_in[23]; a.linb  = (const float*)d_in[24];
  a.adjp  = adjp; a.off = off;
  a.pred  = out;                        // (B,T,2N)
  a.lat   = out + (size_t)4194304;      // (B,T,N,1)
  a.att   = out + (size_t)6291456;      // (T,B,5120,8)
  a.hs=hs; a.runoff=runoff; a.h1=h1; a.s1=s1; a.d1=d1;
  a.h2=h2; a.s2=s2; a.d2=d2; a.xf=xfb; a.gbuf=gbuf;
  a.hn=hn; a.cn=cn; a.bar=bar;

  k_persist<<<NB, 256, 0, stream>>>(a);
}

// Round 12
// 11199.562 us; speedup vs baseline: 1.8954x; 1.4945x over previous
//
#include <hip/hip_runtime.h>
#include <hip/hip_bf16.h>

#define BB 32
#define TT 64
#define NNODE 1024
#define EE 4096
#define NEDGE 5120        // EE + NNODE self loops
#define NHEAD 8
#define HLL 512
#define HRR 64
#define TWO_N 2048
#define KCELL 2560

__device__ __forceinline__ float sigmoidf_(float x){ return 1.f/(1.f+expf(-x)); }
__device__ __forceinline__ float leaky(float x, float s){ return x>0.f? x : s*x; }

// ---------------- CSR by dst (deterministic), packed (src<<13 | eid) ----------------
__global__ __launch_bounds__(1024) void k_csr_off(const int* __restrict__ ei, int* __restrict__ off){
  __shared__ int deg[NNODE];
  __shared__ int scn[NNODE];
  int tid = threadIdx.x;
  deg[tid] = 1;  // self loop
  __syncthreads();
  for(int e=tid; e<EE; e+=1024) atomicAdd(&deg[ei[EE+e]], 1);
  __syncthreads();
  scn[tid] = deg[tid];
  __syncthreads();
  for(int ofs=1; ofs<1024; ofs<<=1){
    int add = (tid>=ofs)? scn[tid-ofs] : 0;
    __syncthreads();
    scn[tid] += add;
    __syncthreads();
  }
  off[tid+1] = scn[tid];
  if(tid==0) off[0] = 0;
}

__global__ __launch_bounds__(1024) void k_csr_fill(const int* __restrict__ ei,
    const int* __restrict__ off, int* __restrict__ adjp){
  __shared__ int dstb[EE];
  int tid = threadIdx.x;
  for(int e=tid; e<EE; e+=1024) dstb[e] = ei[EE+e];
  __syncthreads();
  int e = blockIdx.x*1024 + tid;
  int myd = dstb[e];
  int rank = 0;
  for(int ep=0; ep<e; ep++) rank += (dstb[ep]==myd) ? 1 : 0;
  adjp[off[myd]+rank] = (ei[e] << 13) | e;                          // real edge
  if(blockIdx.x==0) adjp[off[tid+1]-1] = (tid << 13) | (EE + tid);  // self loop last
}

// ---------------- LSTM over T steps, one block per batch ----------------
__global__ __launch_bounds__(256) void k_lstm(
    const float* __restrict__ rain, const float* __restrict__ Wih,
    const float* __restrict__ Whh, const float* __restrict__ bih,
    const float* __restrict__ bhh, float* __restrict__ hs){
  int b = blockIdx.x;
  int j = threadIdx.x;
  __shared__ float h_lds[HRR];
  __shared__ float g_lds[4*HRR];
  float wh[HRR];
  #pragma unroll
  for(int k=0;k<HRR;k++) wh[k] = Whh[j*HRR+k];
  float wi = Wih[j];
  float bias = bih[j] + bhh[j];
  float c = 0.f;
  if(j < HRR) h_lds[j] = 0.f;
  __syncthreads();
  for(int t=0;t<TT;t++){
    float x = rain[b*TT+t];
    float g = fmaf(wi, x, bias);
    #pragma unroll
    for(int k=0;k<HRR;k++) g = fmaf(wh[k], h_lds[k], g);
    g_lds[j] = g;
    __syncthreads();
    if(j < HRR){
      c = sigmoidf_(g_lds[HRR+j])*c + sigmoidf_(g_lds[j])*tanhf(g_lds[2*HRR+j]);
      float h = sigmoidf_(g_lds[3*HRR+j])*tanhf(c);
      h_lds[j] = h;
      hs[(t*BB+b)*HRR + j] = h;
    }
    __syncthreads();
  }
}

// ---------------- runoff = leaky(hs @ fcW^T + fcb), + inflow at node 753 ----------------
__global__ __launch_bounds__(256) void k_runoff(
    const float* __restrict__ hs, const float* __restrict__ fcW,
    const float* __restrict__ fcb, const float* __restrict__ inflow,
    float* __restrict__ runoff, float* __restrict__ lat){
  int p = blockIdx.x;
  int q = p & 3; int tb = p >> 2; int t = tb >> 5; int b = tb & 31;
  int n = q*256 + threadIdx.x;
  __shared__ float hrow[HRR];
  if(threadIdx.x < HRR) hrow[threadIdx.x] = hs[(t*BB+b)*HRR + threadIdx.x];
  __syncthreads();
  const float* wrow = fcW + n*HRR;
  float a0=0,a1=0,a2=0,a3=0;
  #pragma unroll
  for(int k=0;k<HRR;k+=4){
    float4 w = *reinterpret_cast<const float4*>(wrow + k);
    a0 = fmaf(w.x, hrow[k+0], a0);
    a1 = fmaf(w.y, hrow[k+1], a1);
    a2 = fmaf(w.z, hrow[k+2], a2);
    a3 = fmaf(w.w, hrow[k+3], a3);
  }
  float acc = (a0+a1)+(a2+a3) + fcb[n];
  float r = leaky(acc, 0.01f);
  if(n == 753) r += inflow[b*TT + t];
  runoff[(t*BB+b)*NNODE + n] = r;
  lat[(size_t)(b*TT+t)*NNODE + n] = r;
}

// ---------------- merged GAT1+GAT2, one block per batch, fully block-local ----------------
__global__ __launch_bounds__(1024) void k_gat(
    const int* __restrict__ adjp, const int* __restrict__ off,
    const float* __restrict__ xn, const float* __restrict__ runoff,
    const float* __restrict__ g1W, const float* __restrict__ g1as,
    const float* __restrict__ g1ad, const float* __restrict__ g1b,
    const float* __restrict__ g2W, const float* __restrict__ g2as,
    const float* __restrict__ g2ad, const float* __restrict__ g2b,
    float* __restrict__ xf, float* __restrict__ att, int t){
  __shared__ float SA[NNODE*24];     // 96 KB: x1 table, later h2 table (in place)
  __shared__ float SB[NNODE*8];      // 32 KB: phase1 x-table (n*3), later s2 table (n*8)
  __shared__ float SC[640];          // combined weights + params
  const int tid = threadIdx.x;
  const int b = blockIdx.x;
  const int n = tid;

  // SC layout: [0..23] wS1(hd,c) [24..47] wD1(hd,c) [48..119] g1W(72)
  //            [128..511] g2W(384) [512..527] g2as [528..543] g2ad [544..545] g2b [552..575] g1b
  if(tid < 72)  SC[48+tid]  = g1W[tid];
  if(tid >= 128 && tid < 512) SC[tid] = g2W[tid-128];
  if(tid >= 512 && tid < 528) SC[tid] = g2as[tid-512];
  if(tid >= 528 && tid < 544) SC[tid] = g2ad[tid-528];
  if(tid >= 544 && tid < 546) SC[tid] = g2b[tid-544];
  if(tid >= 552 && tid < 576) SC[tid] = g1b[tid-552];
  if(tid >= 576 && tid < 600){                 // wS1/wD1: 24 entries
    int i = tid-576; int hd = i/3, c = i%3;
    float s=0,d=0;
    #pragma unroll
    for(int cc=0;cc<3;cc++){
      float w = g1W[c*24+hd*3+cc];
      s = fmaf(w, g1as[hd*3+cc], s);
      d = fmaf(w, g1ad[hd*3+cc], d);
    }
    SC[i] = s; SC[24+i] = d;
  }
  // x-table
  float x0=0.f, x1v=0.f;
  if(t > 0){ x0 = xn[b*TWO_N+2*n]; x1v = xn[b*TWO_N+2*n+1]; }
  float x2 = runoff[((size_t)t*BB+b)*NNODE + n];
  SB[n*3+0]=x0; SB[n*3+1]=x1v; SB[n*3+2]=x2;
  __syncthreads();

  // ---- GAT1: thread = node, 8 heads ----
  int o0 = off[n], o1 = off[n+1];
  float m1[8], den1[8], dn1[8];
  #pragma unroll
  for(int h=0;h<8;h++){
    m1[h] = -1e30f; den1[h] = 0.f;
    dn1[h] = x0*SC[24+h*3+0] + x1v*SC[24+h*3+1] + x2*SC[24+h*3+2];
  }
  for(int e=o0;e<o1;e++){
    int s = adjp[e]>>13;
    float sx0=SB[s*3], sx1=SB[s*3+1], sx2=SB[s*3+2];
    #pragma unroll
    for(int h=0;h<8;h++){
      float s1 = sx0*SC[h*3+0] + sx1*SC[h*3+1] + sx2*SC[h*3+2];
      float lg = leaky(s1+dn1[h], 0.2f);
      if(lg > m1[h]){ den1[h] *= expf(m1[h]-lg); m1[h] = lg; }
      den1[h] += expf(lg-m1[h]);
    }
  }
  float inv1[8];
  #pragma unroll
  for(int h=0;h<8;h++) inv1[h] = 1.f/(den1[h]+1e-16f);
  float agg[24];
  #pragma unroll
  for(int k=0;k<24;k++) agg[k]=0.f;
  for(int e=o0;e<o1;e++){
    int pk = adjp[e]; int s = pk>>13; int eid = pk & 8191;
    float sx0=SB[s*3], sx1=SB[s*3+1], sx2=SB[s*3+2];
    float at8[8];
    #pragma unroll
    for(int h=0;h<8;h++){
      float s1 = sx0*SC[h*3+0] + sx1*SC[h*3+1] + sx2*SC[h*3+2];
      float lg = leaky(s1+dn1[h], 0.2f);
      float al = expf(lg-m1[h])*inv1[h];
      at8[h] = al;
      #pragma unroll
      for(int cc=0;cc<3;cc++){
        float h1v = sx0*SC[48+h*3+cc] + sx1*SC[48+24+h*3+cc] + sx2*SC[48+48+h*3+cc];
        agg[h*3+cc] = fmaf(al, h1v, agg[h*3+cc]);
      }
    }
    float* ap = att + ((size_t)(t*BB+b)*NEDGE + eid)*NHEAD;
    *reinterpret_cast<float4*>(ap)   = make_float4(at8[0],at8[1],at8[2],at8[3]);
    *reinterpret_cast<float4*>(ap+4) = make_float4(at8[4],at8[5],at8[6],at8[7]);
  }
  // x1 row
  float x1r[24];
  #pragma unroll
  for(int k=0;k<24;k++){
    x1r[k] = leaky(agg[k] + SC[552+k], 0.01f);
  }
  __syncthreads();           // everyone done reading SB x-table & (no SA use yet)

  // ---- build h2 (into SA, n*16), s2 (SB, n*8), d2 (regs) ----
  float h2r[16];
  #pragma unroll
  for(int j=0;j<16;j++) h2r[j]=0.f;
  #pragma unroll
  for(int k=0;k<24;k++){
    float xv = x1r[k];
    #pragma unroll
    for(int j=0;j<16;j++) h2r[j] = fmaf(xv, SC[128+k*16+j], h2r[j]);
  }
  float d2[8];
  #pragma unroll
  for(int h=0;h<8;h++){
    SB[n*8+h] = h2r[2*h]*SC[512+2*h] + h2r[2*h+1]*SC[512+2*h+1];
    d2[h]     = h2r[2*h]*SC[528+2*h] + h2r[2*h+1]*SC[528+2*h+1];
  }
  #pragma unroll
  for(int j=0;j<16;j++) SA[n*16+j] = h2r[j];
  __syncthreads();

  // ---- GAT2: thread = node, 8 heads ----
  float m2[8], den2[8];
  #pragma unroll
  for(int h=0;h<8;h++){ m2[h]=-1e30f; den2[h]=0.f; }
  for(int e=o0;e<o1;e++){
    int s = adjp[e]>>13;
    #pragma unroll
    for(int h=0;h<8;h++){
      float lg = leaky(SB[s*8+h]+d2[h], 0.2f);
      if(lg > m2[h]){ den2[h] *= expf(m2[h]-lg); m2[h] = lg; }
      den2[h] += expf(lg-m2[h]);
    }
  }
  float inv2[8];
  #pragma unroll
  for(int h=0;h<8;h++) inv2[h] = 1.f/(den2[h]+1e-16f);
  float agg2[16];
  #pragma unroll
  for(int j=0;j<16;j++) agg2[j]=0.f;
  for(int e=o0;e<o1;e++){
    int s = adjp[e]>>13;
    #pragma unroll
    for(int h=0;h<8;h++){
      float lg = leaky(SB[s*8+h]+d2[h], 0.2f);
      float al = expf(lg-m2[h])*inv2[h];
      agg2[2*h]   = fmaf(al, SA[s*16+2*h],   agg2[2*h]);
      agg2[2*h+1] = fmaf(al, SA[s*16+2*h+1], agg2[2*h+1]);
    }
  }
  #pragma unroll
  for(int cc=0;cc<2;cc++){
    float acc=0.f;
    #pragma unroll
    for(int h=0;h<8;h++) acc += agg2[2*h+cc];
    xf[b*TWO_N + n*2 + cc] = leaky(acc*0.125f + SC[544+cc], 0.01f);
  }
}

// ---------------- cell GEMM split-K: halves write g0/g1 partials ----------------
__global__ __launch_bounds__(256) void k_cell_gemm(const float* __restrict__ xf,
    const float* __restrict__ hn, const float* __restrict__ Wih, const float* __restrict__ Whh,
    float* __restrict__ g0, float* __restrict__ g1){
  __shared__ float xl[256*33];
  int bid = blockIdx.x;
  int half = bid >> 8; int jb = bid & 255;
  int tid = threadIdx.x;
  int jl = tid >> 5; int b = tid & 31;
  int j = jb*8 + jl;
  float a0=0.f,a1=0.f,a2=0.f,a3=0.f;
  int kbeg = half*1280, kend = kbeg + 1280;
  for(int k0=kbeg; k0<kend; k0+=256){
    if(k0 < TWO_N){
      for(int i=0;i<32;i++) xl[tid*33+i] = xf[i*TWO_N + k0 + tid];
    } else {
      for(int i=0;i<32;i++) xl[tid*33+i] = hn[i*HLL + (k0-TWO_N) + tid];
    }
    __syncthreads();
    const float* wrow = (k0 < TWO_N) ? (Wih + (size_t)j*TWO_N + k0)
                                     : (Whh + (size_t)j*HLL + (k0-TWO_N));
    #pragma unroll 4
    for(int kk=0; kk<256; kk+=8){
      float4 w0 = *reinterpret_cast<const float4*>(wrow + kk);
      float4 w1 = *reinterpret_cast<const float4*>(wrow + kk + 4);
      const float* xp = &xl[kk*33 + b];
      a0 = fmaf(w0.x, xp[0],   a0);
      a1 = fmaf(w0.y, xp[33],  a1);
      a2 = fmaf(w0.z, xp[66],  a2);
      a3 = fmaf(w0.w, xp[99],  a3);
      a0 = fmaf(w1.x, xp[132], a0);
      a1 = fmaf(w1.y, xp[165], a1);
      a2 = fmaf(w1.z, xp[198], a2);
      a3 = fmaf(w1.w, xp[231], a3);
    }
    __syncthreads();
  }
  float* dst = half ? g1 : g0;
  dst[b*TWO_N + j] = (a0+a1)+(a2+a3);
}

// ---------------- gates (sum partials + biases) + LayerNorm ----------------
__global__ __launch_bounds__(512) void k_gateln(const float* __restrict__ g0,
    const float* __restrict__ g1,
    const float* __restrict__ bih, const float* __restrict__ bhh,
    float* __restrict__ cn, float* __restrict__ hn,
    const float* __restrict__ lng, const float* __restrict__ lnb){
  int b = blockIdx.x; int u = threadIdx.x;   // 512
  const float* r0 = g0 + b*TWO_N;
  const float* r1 = g1 + b*TWO_N;
  float gi = r0[u]       + r1[u]       + bih[u]       + bhh[u];
  float gf = r0[HLL+u]   + r1[HLL+u]   + bih[HLL+u]   + bhh[HLL+u];
  float gg = r0[2*HLL+u] + r1[2*HLL+u] + bih[2*HLL+u] + bhh[2*HLL+u];
  float go = r0[3*HLL+u] + r1[3*HLL+u] + bih[3*HLL+u] + bhh[3*HLL+u];
  float c = sigmoidf_(gf)*cn[b*HLL+u] + sigmoidf_(gi)*tanhf(gg);
  cn[b*HLL+u] = c;
  float h = sigmoidf_(go)*tanhf(c);
  __shared__ float red[HLL];
  __shared__ float red2[HLL];
  red[u] = h; red2[u] = h*h;
  __syncthreads();
  for(int s=256; s>0; s>>=1){
    if(u < s){ red[u] += red[u+s]; red2[u] += red2[u+s]; }
    __syncthreads();
  }
  float mu = red[0] * (1.f/HLL);
  float var = red2[0] * (1.f/HLL) - mu*mu;
  float rstd = rsqrtf(var + 1e-5f);
  hn[b*HLL+u] = (h-mu)*rstd*lng[u] + lnb[u];
}

// ---------------- lin GEMM + softplus -> pred(t), xn ----------------
__global__ __launch_bounds__(256) void k_lin(const float* __restrict__ hn,
    const float* __restrict__ W, const float* __restrict__ bias,
    float* __restrict__ pred, float* __restrict__ xn, int t){
  __shared__ float hl[256*33];
  int tid = threadIdx.x;
  int jl = tid >> 5; int b = tid & 31;
  int j = blockIdx.x*8 + jl;
  float a0=0.f,a1=0.f,a2=0.f,a3=0.f;
  for(int k0=0; k0<HLL; k0+=256){
    for(int i=0;i<32;i++) hl[tid*33+i] = hn[i*HLL + k0 + tid];
    __syncthreads();
    const float* wrow = W + (size_t)j*HLL + k0;
    #pragma unroll 4
    for(int kk=0; kk<256; kk+=8){
      float4 w0 = *reinterpret_cast<const float4*>(wrow + kk);
      float4 w1 = *reinterpret_cast<const float4*>(wrow + kk + 4);
      const float* xp = &hl[kk*33 + b];
      a0 = fmaf(w0.x, xp[0],   a0);
      a1 = fmaf(w0.y, xp[33],  a1);
      a2 = fmaf(w0.z, xp[66],  a2);
      a3 = fmaf(w0.w, xp[99],  a3);
      a0 = fmaf(w1.x, xp[132], a0);
      a1 = fmaf(w1.y, xp[165], a1);
      a2 = fmaf(w1.z, xp[198], a2);
      a3 = fmaf(w1.w, xp[231], a3);
    }
    __syncthreads();
  }
  float val = (a0+a1)+(a2+a3) + bias[j];
  float sp = fmaxf(val, 0.f) + log1pf(expf(-fabsf(val)));   // softplus, stable
  pred[((size_t)b*TT + t)*TWO_N + j] = sp;
  xn[b*TWO_N + j] = sp;
}

// ---------------- init hn/cn to zero ----------------
__global__ __launch_bounds__(512) void k_init(float* __restrict__ hn, float* __restrict__ cn){
  int idx = blockIdx.x*512 + threadIdx.x;   // 32768
  if(idx < BB*HLL) hn[idx] = 0.f;
  else cn[idx - BB*HLL] = 0.f;
}

extern "C" void kernel_launch(void* const* d_in, const int* in_sizes, int n_in,
                              void* d_out, int out_size, void* d_ws, size_t ws_size,
                              hipStream_t stream){
  const float* rainfall  = (const float*)d_in[0];
  const float* inflow    = (const float*)d_in[1];
  const int*   edge_index= (const int*)  d_in[2];
  const float* lstm_Wih  = (const float*)d_in[3];
  const float* lstm_Whh  = (const float*)d_in[4];
  const float* lstm_bih  = (const float*)d_in[5];
  const float* lstm_bhh  = (const float*)d_in[6];
  const float* fc_W      = (const float*)d_in[7];
  const float* fc_b      = (const float*)d_in[8];
  const float* g1_W      = (const float*)d_in[9];
  const float* g1_as     = (const float*)d_in[10];
  const float* g1_ad     = (const float*)d_in[11];
  const float* g1_b      = (const float*)d_in[12];
  const float* g2_W      = (const float*)d_in[13];
  const float* g2_as     = (const float*)d_in[14];
  const float* g2_ad     = (const float*)d_in[15];
  const float* g2_b      = (const float*)d_in[16];
  const float* cell_Wih  = (const float*)d_in[17];
  const float* cell_Whh  = (const float*)d_in[18];
  const float* cell_bih  = (const float*)d_in[19];
  const float* cell_bhh  = (const float*)d_in[20];
  const float* ln_g      = (const float*)d_in[21];
  const float* ln_b      = (const float*)d_in[22];
  const float* lin_W     = (const float*)d_in[23];
  const float* lin_b     = (const float*)d_in[24];

  float* out  = (float*)d_out;
  float* pred = out;                       // (B,T,2N) = 4194304
  float* lat  = out + (size_t)4194304;     // (B,T,N,1) = 2097152
  float* att  = out + (size_t)6291456;     // (T,B,5120,8)

  float* ws = (float*)d_ws;
  float* hs     = ws;                        // 131072
  float* runoff = hs + 131072;               // 2097152
  float* xnb    = runoff + 2097152;          // 65536
  float* xfb    = xnb + 65536;               // 65536
  float* g0buf  = xfb + 65536;               // 65536
  float* g1buf  = g0buf + 65536;             // 65536
  float* hn     = g1buf + 65536;             // 16384
  float* cn     = hn + 16384;                // 16384
  int*   off    = (int*)(cn + 16384);        // 1025 (pad 1032)
  int*   adjp   = off + 1032;                // 5120
  if(ws_size < 10117152ull) return;          // diagnostic: zero output

  k_init<<<64, 512, 0, stream>>>(hn, cn);
  k_csr_off<<<1, 1024, 0, stream>>>(edge_index, off);
  k_csr_fill<<<4, 1024, 0, stream>>>(edge_index, off, adjp);
  k_lstm<<<BB, 256, 0, stream>>>(rainfall, lstm_Wih, lstm_Whh, lstm_bih, lstm_bhh, hs);
  k_runoff<<<TT*BB*4, 256, 0, stream>>>(hs, fc_W, fc_b, inflow, runoff, lat);

  for(int t=0; t<TT; t++){
    k_gat<<<BB, 1024, 0, stream>>>(adjp, off, xnb, runoff,
        g1_W, g1_as, g1_ad, g1_b, g2_W, g2_as, g2_ad, g2_b, xfb, att, t);
    k_cell_gemm<<<512, 256, 0, stream>>>(xfb, hn, cell_Wih, cell_Whh, g0buf, g1buf);
    k_gateln<<<BB, 512, 0, stream>>>(g0buf, g1buf, cell_bih, cell_bhh, cn, hn, ln_g, ln_b);
    k_lin<<<256, 256, 0, stream>>>(hn, lin_W, lin_b, pred, xnb, t);
  }
}

// Round 13
// 9159.926 us; speedup vs baseline: 2.3174x; 1.2227x over previous
//
#include <hip/hip_runtime.h>
#include <hip/hip_bf16.h>

#define BB 32
#define TT 64
#define NNODE 1024
#define EE 4096
#define NEDGE 5120        // EE + NNODE self loops
#define NHEAD 8
#define HLL 512
#define HRR 64
#define TWO_N 2048
#define KCELL 2560

__device__ __forceinline__ float sigmoidf_(float x){ return 1.f/(1.f+expf(-x)); }
__device__ __forceinline__ float leaky(float x, float s){ return x>0.f? x : s*x; }

// ---------------- CSR by dst (deterministic), packed (src<<13 | eid) ----------------
__global__ __launch_bounds__(1024) void k_csr_off(const int* __restrict__ ei, int* __restrict__ off){
  __shared__ int deg[NNODE];
  __shared__ int scn[NNODE];
  int tid = threadIdx.x;
  deg[tid] = 1;  // self loop
  __syncthreads();
  for(int e=tid; e<EE; e+=1024) atomicAdd(&deg[ei[EE+e]], 1);
  __syncthreads();
  scn[tid] = deg[tid];
  __syncthreads();
  for(int ofs=1; ofs<1024; ofs<<=1){
    int add = (tid>=ofs)? scn[tid-ofs] : 0;
    __syncthreads();
    scn[tid] += add;
    __syncthreads();
  }
  off[tid+1] = scn[tid];
  if(tid==0) off[0] = 0;
}

__global__ __launch_bounds__(1024) void k_csr_fill(const int* __restrict__ ei,
    const int* __restrict__ off, int* __restrict__ adjp){
  __shared__ int dstb[EE];
  int tid = threadIdx.x;
  for(int e=tid; e<EE; e+=1024) dstb[e] = ei[EE+e];
  __syncthreads();
  int e = blockIdx.x*1024 + tid;
  int myd = dstb[e];
  int rank = 0;
  for(int ep=0; ep<e; ep++) rank += (dstb[ep]==myd) ? 1 : 0;
  adjp[off[myd]+rank] = (ei[e] << 13) | e;                          // real edge
  if(blockIdx.x==0) adjp[off[tid+1]-1] = (tid << 13) | (EE + tid);  // self loop last
}

// ---------------- LSTM over T steps, one block per batch ----------------
__global__ __launch_bounds__(256) void k_lstm(
    const float* __restrict__ rain, const float* __restrict__ Wih,
    const float* __restrict__ Whh, const float* __restrict__ bih,
    const float* __restrict__ bhh, float* __restrict__ hs){
  int b = blockIdx.x;
  int j = threadIdx.x;
  __shared__ float h_lds[HRR];
  __shared__ float g_lds[4*HRR];
  float wh[HRR];
  #pragma unroll
  for(int k=0;k<HRR;k++) wh[k] = Whh[j*HRR+k];
  float wi = Wih[j];
  float bias = bih[j] + bhh[j];
  float c = 0.f;
  if(j < HRR) h_lds[j] = 0.f;
  __syncthreads();
  for(int t=0;t<TT;t++){
    float x = rain[b*TT+t];
    float g = fmaf(wi, x, bias);
    #pragma unroll
    for(int k=0;k<HRR;k++) g = fmaf(wh[k], h_lds[k], g);
    g_lds[j] = g;
    __syncthreads();
    if(j < HRR){
      c = sigmoidf_(g_lds[HRR+j])*c + sigmoidf_(g_lds[j])*tanhf(g_lds[2*HRR+j]);
      float h = sigmoidf_(g_lds[3*HRR+j])*tanhf(c);
      h_lds[j] = h;
      hs[(t*BB+b)*HRR + j] = h;
    }
    __syncthreads();
  }
}

// ---------------- runoff = leaky(hs @ fcW^T + fcb), + inflow at node 753 ----------------
__global__ __launch_bounds__(256) void k_runoff(
    const float* __restrict__ hs, const float* __restrict__ fcW,
    const float* __restrict__ fcb, const float* __restrict__ inflow,
    float* __restrict__ runoff, float* __restrict__ lat){
  int p = blockIdx.x;
  int q = p & 3; int tb = p >> 2; int t = tb >> 5; int b = tb & 31;
  int n = q*256 + threadIdx.x;
  __shared__ float hrow[HRR];
  if(threadIdx.x < HRR) hrow[threadIdx.x] = hs[(t*BB+b)*HRR + threadIdx.x];
  __syncthreads();
  const float* wrow = fcW + n*HRR;
  float a0=0,a1=0,a2=0,a3=0;
  #pragma unroll
  for(int k=0;k<HRR;k+=4){
    float4 w = *reinterpret_cast<const float4*>(wrow + k);
    a0 = fmaf(w.x, hrow[k+0], a0);
    a1 = fmaf(w.y, hrow[k+1], a1);
    a2 = fmaf(w.z, hrow[k+2], a2);
    a3 = fmaf(w.w, hrow[k+3], a3);
  }
  float acc = (a0+a1)+(a2+a3) + fcb[n];
  float r = leaky(acc, 0.01f);
  if(n == 753) r += inflow[b*TT + t];
  runoff[(t*BB+b)*NNODE + n] = r;
  lat[(size_t)(b*TT+t)*NNODE + n] = r;
}

// ---------------- merged GAT1+GAT2, one block per batch, head-split (no spills) ----------------
__global__ __launch_bounds__(1024) void k_gat(
    const int* __restrict__ adjp, const int* __restrict__ off,
    const float* __restrict__ xn, const float* __restrict__ runoff,
    const float* __restrict__ g1W, const float* __restrict__ g1as,
    const float* __restrict__ g1ad, const float* __restrict__ g1b,
    const float* __restrict__ g2W, const float* __restrict__ g2as,
    const float* __restrict__ g2ad, const float* __restrict__ g2b,
    float* __restrict__ xf, float* __restrict__ att, int t){
  __shared__ float SA[NNODE*16];     // 64 KB: h2 table
  __shared__ float SB[NNODE*8];      // 32 KB: x-table (n*3), later s2 table (n*8)
  __shared__ float SC[640];          // combined weights + params
  const int tid = threadIdx.x;
  const int b = blockIdx.x;
  const int n = tid;

  // SC layout: [0..23] wS1(hd,c) [24..47] wD1(hd,c) [48..119] g1W(72)
  //            [128..511] g2W(384) [512..527] g2as [528..543] g2ad [544..545] g2b [552..575] g1b
  if(tid < 72)  SC[48+tid]  = g1W[tid];
  if(tid >= 128 && tid < 512) SC[tid] = g2W[tid-128];
  if(tid >= 512 && tid < 528) SC[tid] = g2as[tid-512];
  if(tid >= 528 && tid < 544) SC[tid] = g2ad[tid-528];
  if(tid >= 544 && tid < 546) SC[tid] = g2b[tid-544];
  if(tid >= 552 && tid < 576) SC[tid] = g1b[tid-552];
  if(tid >= 576 && tid < 600){                 // wS1/wD1: 24 entries
    int i = tid-576; int hd = i/3, c = i%3;
    float s=0,d=0;
    #pragma unroll
    for(int cc=0;cc<3;cc++){
      float w = g1W[c*24+hd*3+cc];
      s = fmaf(w, g1as[hd*3+cc], s);
      d = fmaf(w, g1ad[hd*3+cc], d);
    }
    SC[i] = s; SC[24+i] = d;
  }
  float x0=0.f, x1v=0.f;
  if(t > 0){ x0 = xn[b*TWO_N+2*n]; x1v = xn[b*TWO_N+2*n+1]; }
  float x2 = runoff[((size_t)t*BB+b)*NNODE + n];
  SB[n*3+0]=x0; SB[n*3+1]=x1v; SB[n*3+2]=x2;
  __syncthreads();

  const int o0 = off[n], o1 = off[n+1];
  float h2r[16];
  #pragma unroll
  for(int j=0;j<16;j++) h2r[j]=0.f;

  // ---- GAT1: two head-halves of 4 ----
  #pragma unroll 1
  for(int hh=0; hh<2; hh++){
    const int hb = hh*4;
    float m1[4], den1[4], dn1[4];
    #pragma unroll
    for(int q=0;q<4;q++){
      int h = hb+q;
      m1[q] = -1e30f; den1[q] = 0.f;
      dn1[q] = x0*SC[24+h*3+0] + x1v*SC[24+h*3+1] + x2*SC[24+h*3+2];
    }
    for(int e=o0;e<o1;e++){
      int s = adjp[e]>>13;
      float sx0=SB[s*3], sx1=SB[s*3+1], sx2=SB[s*3+2];
      #pragma unroll
      for(int q=0;q<4;q++){
        int h = hb+q;
        float s1 = sx0*SC[h*3+0] + sx1*SC[h*3+1] + sx2*SC[h*3+2];
        float lg = leaky(s1+dn1[q], 0.2f);
        if(lg > m1[q]){ den1[q] *= expf(m1[q]-lg); m1[q] = lg; }
        den1[q] += expf(lg-m1[q]);
      }
    }
    float inv1[4];
    #pragma unroll
    for(int q=0;q<4;q++) inv1[q] = 1.f/(den1[q]+1e-16f);
    float agg[12];
    #pragma unroll
    for(int k=0;k<12;k++) agg[k]=0.f;
    for(int e=o0;e<o1;e++){
      int pk = adjp[e]; int s = pk>>13; int eid = pk & 8191;
      float sx0=SB[s*3], sx1=SB[s*3+1], sx2=SB[s*3+2];
      float at4[4];
      #pragma unroll
      for(int q=0;q<4;q++){
        int h = hb+q;
        float s1 = sx0*SC[h*3+0] + sx1*SC[h*3+1] + sx2*SC[h*3+2];
        float lg = leaky(s1+dn1[q], 0.2f);
        float al = expf(lg-m1[q])*inv1[q];
        at4[q] = al;
        #pragma unroll
        for(int cc=0;cc<3;cc++){
          float h1v = sx0*SC[48+h*3+cc] + sx1*SC[72+h*3+cc] + sx2*SC[96+h*3+cc];
          agg[q*3+cc] = fmaf(al, h1v, agg[q*3+cc]);
        }
      }
      float* ap = att + ((size_t)(t*BB+b)*NEDGE + eid)*NHEAD + hb;
      *reinterpret_cast<float4*>(ap) = make_float4(at4[0],at4[1],at4[2],at4[3]);
    }
    // x1 (this half) -> fold into h2r immediately (x1 never materialized)
    #pragma unroll
    for(int q=0;q<4;q++){
      #pragma unroll
      for(int cc=0;cc<3;cc++){
        int k = (hb+q)*3+cc;
        float x1k = leaky(agg[q*3+cc] + SC[552+k], 0.01f);
        #pragma unroll
        for(int j=0;j<16;j++) h2r[j] = fmaf(x1k, SC[128+k*16+j], h2r[j]);
      }
    }
  }
  __syncthreads();           // all GAT1 reads of SB x-table done

  // ---- publish h2 (SA), s2 (SB); keep d2 in regs ----
  float d2[8];
  #pragma unroll
  for(int h=0;h<8;h++){
    SB[n*8+h] = h2r[2*h]*SC[512+2*h] + h2r[2*h+1]*SC[512+2*h+1];
    d2[h]     = h2r[2*h]*SC[528+2*h] + h2r[2*h+1]*SC[528+2*h+1];
  }
  #pragma unroll
  for(int j=0;j<16;j++) SA[n*16+j] = h2r[j];
  __syncthreads();

  // ---- GAT2: two head-halves of 4 ----
  float xfa0=0.f, xfa1=0.f;
  #pragma unroll 1
  for(int hh=0;hh<2;hh++){
    const int hb = hh*4;
    float m2[4], den2[4];
    #pragma unroll
    for(int q=0;q<4;q++){ m2[q]=-1e30f; den2[q]=0.f; }
    for(int e=o0;e<o1;e++){
      int s = adjp[e]>>13;
      #pragma unroll
      for(int q=0;q<4;q++){
        float lg = leaky(SB[s*8+hb+q]+d2[hb+q], 0.2f);
        if(lg > m2[q]){ den2[q] *= expf(m2[q]-lg); m2[q] = lg; }
        den2[q] += expf(lg-m2[q]);
      }
    }
    float inv2[4];
    #pragma unroll
    for(int q=0;q<4;q++) inv2[q] = 1.f/(den2[q]+1e-16f);
    float agg2[8];
    #pragma unroll
    for(int j=0;j<8;j++) agg2[j]=0.f;
    for(int e=o0;e<o1;e++){
      int s = adjp[e]>>13;
      #pragma unroll
      for(int q=0;q<4;q++){
        int h = hb+q;
        float lg = leaky(SB[s*8+h]+d2[h], 0.2f);
        float al = expf(lg-m2[q])*inv2[q];
        agg2[2*q]   = fmaf(al, SA[s*16+2*h],   agg2[2*q]);
        agg2[2*q+1] = fmaf(al, SA[s*16+2*h+1], agg2[2*q+1]);
      }
    }
    #pragma unroll
    for(int q=0;q<4;q++){ xfa0 += agg2[2*q]; xfa1 += agg2[2*q+1]; }
  }
  xf[b*TWO_N + n*2 + 0] = leaky(xfa0*0.125f + SC[544], 0.01f);
  xf[b*TWO_N + n*2 + 1] = leaky(xfa1*0.125f + SC[545], 0.01f);
}

// ---------------- cell GEMM split-K, 2 j-rows per thread ----------------
__global__ __launch_bounds__(256) void k_cell_gemm(const float* __restrict__ xf,
    const float* __restrict__ hn, const float* __restrict__ Wih, const float* __restrict__ Whh,
    float* __restrict__ g0, float* __restrict__ g1){
  __shared__ float xl[256*33];
  int bid = blockIdx.x;
  int half = bid >> 7; int jb = bid & 127;
  int tid = threadIdx.x;
  int jl = tid >> 5; int b = tid & 31;
  int j0 = jb*16 + jl*2;
  float a00=0,a01=0,a02=0,a03=0, a10=0,a11=0,a12=0,a13=0;
  int kbeg = half*1280, kend = kbeg + 1280;
  for(int k0=kbeg; k0<kend; k0+=256){
    if(k0 < TWO_N){
      for(int i=0;i<32;i++) xl[tid*33+i] = xf[i*TWO_N + k0 + tid];
    } else {
      for(int i=0;i<32;i++) xl[tid*33+i] = hn[i*HLL + (k0-TWO_N) + tid];
    }
    __syncthreads();
    const float* wr0;
    const float* wr1;
    if(k0 < TWO_N){
      wr0 = Wih + (size_t)j0*TWO_N + k0;
      wr1 = Wih + (size_t)(j0+1)*TWO_N + k0;
    } else {
      wr0 = Whh + (size_t)j0*HLL + (k0-TWO_N);
      wr1 = Whh + (size_t)(j0+1)*HLL + (k0-TWO_N);
    }
    #pragma unroll 4
    for(int kk=0; kk<256; kk+=8){
      float4 w00 = *reinterpret_cast<const float4*>(wr0 + kk);
      float4 w01 = *reinterpret_cast<const float4*>(wr0 + kk + 4);
      float4 w10 = *reinterpret_cast<const float4*>(wr1 + kk);
      float4 w11 = *reinterpret_cast<const float4*>(wr1 + kk + 4);
      const float* xp = &xl[kk*33 + b];
      float xv0=xp[0], xv1=xp[33], xv2=xp[66], xv3=xp[99];
      float xv4=xp[132], xv5=xp[165], xv6=xp[198], xv7=xp[231];
      a00 = fmaf(w00.x, xv0, a00);  a10 = fmaf(w10.x, xv0, a10);
      a01 = fmaf(w00.y, xv1, a01);  a11 = fmaf(w10.y, xv1, a11);
      a02 = fmaf(w00.z, xv2, a02);  a12 = fmaf(w10.z, xv2, a12);
      a03 = fmaf(w00.w, xv3, a03);  a13 = fmaf(w10.w, xv3, a13);
      a00 = fmaf(w01.x, xv4, a00);  a10 = fmaf(w11.x, xv4, a10);
      a01 = fmaf(w01.y, xv5, a01);  a11 = fmaf(w11.y, xv5, a11);
      a02 = fmaf(w01.z, xv6, a02);  a12 = fmaf(w11.z, xv6, a12);
      a03 = fmaf(w01.w, xv7, a03);  a13 = fmaf(w11.w, xv7, a13);
    }
    __syncthreads();
  }
  float* dst = half ? g1 : g0;
  dst[b*TWO_N + j0]     = (a00+a01)+(a02+a03);
  dst[b*TWO_N + j0 + 1] = (a10+a11)+(a12+a13);
}

// ---------------- gates (sum partials + biases) + LayerNorm ----------------
__global__ __launch_bounds__(512) void k_gateln(const float* __restrict__ g0,
    const float* __restrict__ g1,
    const float* __restrict__ bih, const float* __restrict__ bhh,
    float* __restrict__ cn, float* __restrict__ hn,
    const float* __restrict__ lng, const float* __restrict__ lnb){
  int b = blockIdx.x; int u = threadIdx.x;   // 512
  const float* r0 = g0 + b*TWO_N;
  const float* r1 = g1 + b*TWO_N;
  float gi = r0[u]       + r1[u]       + bih[u]       + bhh[u];
  float gf = r0[HLL+u]   + r1[HLL+u]   + bih[HLL+u]   + bhh[HLL+u];
  float gg = r0[2*HLL+u] + r1[2*HLL+u] + bih[2*HLL+u] + bhh[2*HLL+u];
  float go = r0[3*HLL+u] + r1[3*HLL+u] + bih[3*HLL+u] + bhh[3*HLL+u];
  float c = sigmoidf_(gf)*cn[b*HLL+u] + sigmoidf_(gi)*tanhf(gg);
  cn[b*HLL+u] = c;
  float h = sigmoidf_(go)*tanhf(c);
  __shared__ float red[HLL];
  __shared__ float red2[HLL];
  red[u] = h; red2[u] = h*h;
  __syncthreads();
  for(int s=256; s>0; s>>=1){
    if(u < s){ red[u] += red[u+s]; red2[u] += red2[u+s]; }
    __syncthreads();
  }
  float mu = red[0] * (1.f/HLL);
  float var = red2[0] * (1.f/HLL) - mu*mu;
  float rstd = rsqrtf(var + 1e-5f);
  hn[b*HLL+u] = (h-mu)*rstd*lng[u] + lnb[u];
}

// ---------------- lin GEMM + softplus -> pred(t), xn ----------------
__global__ __launch_bounds__(256) void k_lin(const float* __restrict__ hn,
    const float* __restrict__ W, const float* __restrict__ bias,
    float* __restrict__ pred, float* __restrict__ xn, int t){
  __shared__ float hl[256*33];
  int tid = threadIdx.x;
  int jl = tid >> 5; int b = tid & 31;
  int j = blockIdx.x*8 + jl;
  float a0=0.f,a1=0.f,a2=0.f,a3=0.f;
  for(int k0=0; k0<HLL; k0+=256){
    for(int i=0;i<32;i++) hl[tid*33+i] = hn[i*HLL + k0 + tid];
    __syncthreads();
    const float* wrow = W + (size_t)j*HLL + k0;
    #pragma unroll 4
    for(int kk=0; kk<256; kk+=8){
      float4 w0 = *reinterpret_cast<const float4*>(wrow + kk);
      float4 w1 = *reinterpret_cast<const float4*>(wrow + kk + 4);
      const float* xp = &hl[kk*33 + b];
      a0 = fmaf(w0.x, xp[0],   a0);
      a1 = fmaf(w0.y, xp[33],  a1);
      a2 = fmaf(w0.z, xp[66],  a2);
      a3 = fmaf(w0.w, xp[99],  a3);
      a0 = fmaf(w1.x, xp[132], a0);
      a1 = fmaf(w1.y, xp[165], a1);
      a2 = fmaf(w1.z, xp[198], a2);
      a3 = fmaf(w1.w, xp[231], a3);
    }
    __syncthreads();
  }
  float val = (a0+a1)+(a2+a3) + bias[j];
  float sp = fmaxf(val, 0.f) + log1pf(expf(-fabsf(val)));   // softplus, stable
  pred[((size_t)b*TT + t)*TWO_N + j] = sp;
  xn[b*TWO_N + j] = sp;
}

// ---------------- init hn/cn to zero ----------------
__global__ __launch_bounds__(512) void k_init(float* __restrict__ hn, float* __restrict__ cn){
  int idx = blockIdx.x*512 + threadIdx.x;   // 32768
  if(idx < BB*HLL) hn[idx] = 0.f;
  else cn[idx - BB*HLL] = 0.f;
}

extern "C" void kernel_launch(void* const* d_in, const int* in_sizes, int n_in,
                              void* d_out, int out_size, void* d_ws, size_t ws_size,
                              hipStream_t stream){
  const float* rainfall  = (const float*)d_in[0];
  const float* inflow    = (const float*)d_in[1];
  const int*   edge_index= (const int*)  d_in[2];
  const float* lstm_Wih  = (const float*)d_in[3];
  const float* lstm_Whh  = (const float*)d_in[4];
  const float* lstm_bih  = (const float*)d_in[5];
  const float* lstm_bhh  = (const float*)d_in[6];
  const float* fc_W      = (const float*)d_in[7];
  const float* fc_b      = (const float*)d_in[8];
  const float* g1_W      = (const float*)d_in[9];
  const float* g1_as     = (const float*)d_in[10];
  const float* g1_ad     = (const float*)d_in[11];
  const float* g1_b      = (const float*)d_in[12];
  const float* g2_W      = (const float*)d_in[13];
  const float* g2_as     = (const float*)d_in[14];
  const float* g2_ad     = (const float*)d_in[15];
  const float* g2_b      = (const float*)d_in[16];
  const float* cell_Wih  = (const float*)d_in[17];
  const float* cell_Whh  = (const float*)d_in[18];
  const float* cell_bih  = (const float*)d_in[19];
  const float* cell_bhh  = (const float*)d_in[20];
  const float* ln_g      = (const float*)d_in[21];
  const float* ln_b      = (const float*)d_in[22];
  const float* lin_W     = (const float*)d_in[23];
  const float* lin_b     = (const float*)d_in[24];

  float* out  = (float*)d_out;
  float* pred = out;                       // (B,T,2N) = 4194304
  float* lat  = out + (size_t)4194304;     // (B,T,N,1) = 2097152
  float* att  = out + (size_t)6291456;     // (T,B,5120,8)

  float* ws = (float*)d_ws;
  float* hs     = ws;                        // 131072
  float* runoff = hs + 131072;               // 2097152
  float* xnb    = runoff + 2097152;          // 65536
  float* xfb    = xnb + 65536;               // 65536
  float* g0buf  = xfb + 65536;               // 65536
  float* g1buf  = g0buf + 65536;             // 65536
  float* hn     = g1buf + 65536;             // 16384
  float* cn     = hn + 16384;                // 16384
  int*   off    = (int*)(cn + 16384);        // 1025 (pad 1032)
  int*   adjp   = off + 1032;                // 5120
  if(ws_size < 10117152ull) return;          // diagnostic: zero output

  k_init<<<64, 512, 0, stream>>>(hn, cn);
  k_csr_off<<<1, 1024, 0, stream>>>(edge_index, off);
  k_csr_fill<<<4, 1024, 0, stream>>>(edge_index, off, adjp);
  k_lstm<<<BB, 256, 0, stream>>>(rainfall, lstm_Wih, lstm_Whh, lstm_bih, lstm_bhh, hs);
  k_runoff<<<TT*BB*4, 256, 0, stream>>>(hs, fc_W, fc_b, inflow, runoff, lat);

  for(int t=0; t<TT; t++){
    k_gat<<<BB, 1024, 0, stream>>>(adjp, off, xnb, runoff,
        g1_W, g1_as, g1_ad, g1_b, g2_W, g2_as, g2_ad, g2_b, xfb, att, t);
    k_cell_gemm<<<256, 256, 0, stream>>>(xfb, hn, cell_Wih, cell_Whh, g0buf, g1buf);
    k_gateln<<<BB, 512, 0, stream>>>(g0buf, g1buf, cell_bih, cell_bhh, cn, hn, ln_g, ln_b);
    k_lin<<<256, 256, 0, stream>>>(hn, lin_W, lin_b, pred, xnb, t);
  }
}

// Round 14
// 6363.446 us; speedup vs baseline: 3.3358x; 1.4395x over previous
//
#include <hip/hip_runtime.h>
#include <hip/hip_bf16.h>

#define BB 32
#define TT 64
#define NNODE 1024
#define EE 4096
#define NEDGE 5120        // EE + NNODE self loops
#define NHEAD 8
#define HLL 512
#define HRR 64
#define TWO_N 2048
#define KCELL 2560

__device__ __forceinline__ float sigmoidf_(float x){ return 1.f/(1.f+expf(-x)); }
__device__ __forceinline__ float leaky(float x, float s){ return x>0.f? x : s*x; }

// ---------------- CSR by dst (deterministic), packed (src<<13 | eid) ----------------
__global__ __launch_bounds__(1024) void k_csr_off(const int* __restrict__ ei, int* __restrict__ off){
  __shared__ int deg[NNODE];
  __shared__ int scn[NNODE];
  int tid = threadIdx.x;
  deg[tid] = 1;  // self loop
  __syncthreads();
  for(int e=tid; e<EE; e+=1024) atomicAdd(&deg[ei[EE+e]], 1);
  __syncthreads();
  scn[tid] = deg[tid];
  __syncthreads();
  for(int ofs=1; ofs<1024; ofs<<=1){
    int add = (tid>=ofs)? scn[tid-ofs] : 0;
    __syncthreads();
    scn[tid] += add;
    __syncthreads();
  }
  off[tid+1] = scn[tid];
  if(tid==0) off[0] = 0;
}

__global__ __launch_bounds__(1024) void k_csr_fill(const int* __restrict__ ei,
    const int* __restrict__ off, int* __restrict__ adjp){
  __shared__ int dstb[EE];
  int tid = threadIdx.x;
  for(int e=tid; e<EE; e+=1024) dstb[e] = ei[EE+e];
  __syncthreads();
  int e = blockIdx.x*1024 + tid;
  int myd = dstb[e];
  int rank = 0;
  for(int ep=0; ep<e; ep++) rank += (dstb[ep]==myd) ? 1 : 0;
  adjp[off[myd]+rank] = (ei[e] << 13) | e;                          // real edge
  if(blockIdx.x==0) adjp[off[tid+1]-1] = (tid << 13) | (EE + tid);  // self loop last
}

// ---------------- LSTM over T steps, one block per batch ----------------
__global__ __launch_bounds__(256) void k_lstm(
    const float* __restrict__ rain, const float* __restrict__ Wih,
    const float* __restrict__ Whh, const float* __restrict__ bih,
    const float* __restrict__ bhh, float* __restrict__ hs){
  int b = blockIdx.x;
  int j = threadIdx.x;
  __shared__ float h_lds[HRR];
  __shared__ float g_lds[4*HRR];
  float wh[HRR];
  #pragma unroll
  for(int k=0;k<HRR;k++) wh[k] = Whh[j*HRR+k];
  float wi = Wih[j];
  float bias = bih[j] + bhh[j];
  float c = 0.f;
  if(j < HRR) h_lds[j] = 0.f;
  __syncthreads();
  for(int t=0;t<TT;t++){
    float x = rain[b*TT+t];
    float g = fmaf(wi, x, bias);
    #pragma unroll
    for(int k=0;k<HRR;k++) g = fmaf(wh[k], h_lds[k], g);
    g_lds[j] = g;
    __syncthreads();
    if(j < HRR){
      c = sigmoidf_(g_lds[HRR+j])*c + sigmoidf_(g_lds[j])*tanhf(g_lds[2*HRR+j]);
      float h = sigmoidf_(g_lds[3*HRR+j])*tanhf(c);
      h_lds[j] = h;
      hs[(t*BB+b)*HRR + j] = h;
    }
    __syncthreads();
  }
}

// ---------------- runoff = leaky(hs @ fcW^T + fcb), + inflow at node 753 ----------------
__global__ __launch_bounds__(256) void k_runoff(
    const float* __restrict__ hs, const float* __restrict__ fcW,
    const float* __restrict__ fcb, const float* __restrict__ inflow,
    float* __restrict__ runoff, float* __restrict__ lat){
  int p = blockIdx.x;
  int q = p & 3; int tb = p >> 2; int t = tb >> 5; int b = tb & 31;
  int n = q*256 + threadIdx.x;
  __shared__ float hrow[HRR];
  if(threadIdx.x < HRR) hrow[threadIdx.x] = hs[(t*BB+b)*HRR + threadIdx.x];
  __syncthreads();
  const float* wrow = fcW + n*HRR;
  float a0=0,a1=0,a2=0,a3=0;
  #pragma unroll
  for(int k=0;k<HRR;k+=4){
    float4 w = *reinterpret_cast<const float4*>(wrow + k);
    a0 = fmaf(w.x, hrow[k+0], a0);
    a1 = fmaf(w.y, hrow[k+1], a1);
    a2 = fmaf(w.z, hrow[k+2], a2);
    a3 = fmaf(w.w, hrow[k+3], a3);
  }
  float acc = (a0+a1)+(a2+a3) + fcb[n];
  float r = leaky(acc, 0.01f);
  if(n == 753) r += inflow[b*TT + t];
  runoff[(t*BB+b)*NNODE + n] = r;
  lat[(size_t)(b*TT+t)*NNODE + n] = r;
}

// ---------------- GAT1 node prep for t=0 ----------------
__global__ __launch_bounds__(256) void k_prep0(const float* __restrict__ runoff,
    const float* __restrict__ g1W, const float* __restrict__ g1as, const float* __restrict__ g1ad,
    float* __restrict__ h1, float* __restrict__ s1, float* __restrict__ d1){
  int idx = blockIdx.x*256 + threadIdx.x;    // 32768 = B*N
  int b = idx >> 10; int n = idx & 1023;
  float x2 = runoff[b*NNODE + n];            // t=0
  float hv[24];
  size_t base = (size_t)b*NNODE + n;
  #pragma unroll
  for(int o=0;o<24;o++){
    hv[o] = x2*g1W[48+o];
    h1[base*24+o] = hv[o];
  }
  #pragma unroll
  for(int hd=0; hd<NHEAD; hd++){
    float s=0.f, d=0.f;
    #pragma unroll
    for(int c=0;c<3;c++){
      float v = hv[hd*3+c];
      s = fmaf(v, g1as[hd*3+c], s);
      d = fmaf(v, g1ad[hd*3+c], d);
    }
    s1[base*8+hd] = s; d1[base*8+hd] = d;
  }
}

// ---------------- GAT1 edge pass (2-pass online softmax, LDS s-table) + GAT2 prep ----------------
__global__ __launch_bounds__(256) void k_gat1f(
    const int* __restrict__ adjp, const int* __restrict__ off,
    const float* __restrict__ h1, const float* __restrict__ s1, const float* __restrict__ d1,
    const float* __restrict__ g1b, const float* __restrict__ g2W,
    const float* __restrict__ g2as, const float* __restrict__ g2ad,
    float* __restrict__ h2, float* __restrict__ s2, float* __restrict__ d2,
    float* __restrict__ att, int t){
  int tid = threadIdx.x;
  int g = tid >> 3; int hd = tid & 7;
  int p = blockIdx.x*32 + g;                 // (b,n); all groups in a block share b
  int b = p >> 10; int n = p & 1023;
  __shared__ float ss[NNODE*NHEAD];          // 32 KB: s1 for this b
  __shared__ float x1buf[32][25];
  size_t bbase = (size_t)b*NNODE;
  for(int i=tid; i<NNODE*NHEAD; i+=256) ss[i] = s1[bbase*8 + i];
  __syncthreads();
  int o0 = off[n], o1 = off[n+1];
  float dn = d1[(bbase+n)*8+hd];
  float m = -1e30f, den = 0.f;
  for(int idx=o0; idx<o1; idx++){
    int pk = adjp[idx]; int s = pk >> 13;
    float lg = leaky(ss[s*8+hd] + dn, 0.2f);
    if(lg > m){ den *= expf(m - lg); m = lg; }
    den += expf(lg - m);
  }
  float inv = 1.f/(den + 1e-16f);
  float o_0=0.f, o_1=0.f, o_2=0.f;
  for(int idx=o0; idx<o1; idx++){
    int pk = adjp[idx]; int s = pk >> 13; int eid = pk & 8191;
    float lg = leaky(ss[s*8+hd] + dn, 0.2f);
    float al = expf(lg - m)*inv;
    att[((size_t)(t*BB+b)*NEDGE + eid)*NHEAD + hd] = al;
    const float* hr = h1 + (bbase+s)*24 + hd*3;
    o_0 = fmaf(hr[0], al, o_0);
    o_1 = fmaf(hr[1], al, o_1);
    o_2 = fmaf(hr[2], al, o_2);
  }
  x1buf[g][hd*3+0] = leaky(o_0 + g1b[hd*3+0], 0.01f);
  x1buf[g][hd*3+1] = leaky(o_1 + g1b[hd*3+1], 0.01f);
  x1buf[g][hd*3+2] = leaky(o_2 + g1b[hd*3+2], 0.01f);
  __syncthreads();
  // GAT2 node prep: h2 (16), s2/d2 (8)
  float h2v0=0.f, h2v1=0.f;
  int oA = hd*2, oB = hd*2+1;
  #pragma unroll
  for(int k=0;k<24;k++){
    float xv = x1buf[g][k];
    h2v0 = fmaf(xv, g2W[k*16+oA], h2v0);
    h2v1 = fmaf(xv, g2W[k*16+oB], h2v1);
  }
  h2[(bbase+n)*16+oA] = h2v0;
  h2[(bbase+n)*16+oB] = h2v1;
  s2[(bbase+n)*8+hd] = h2v0*g2as[oA] + h2v1*g2as[oB];
  d2[(bbase+n)*8+hd] = h2v0*g2ad[oA] + h2v1*g2ad[oB];
}

// ---------------- GAT2 edge pass (2-pass online softmax, LDS s-table) -> xf ----------------
__global__ __launch_bounds__(256) void k_gat2f(
    const int* __restrict__ adjp, const int* __restrict__ off,
    const float* __restrict__ h2, const float* __restrict__ s2, const float* __restrict__ d2,
    const float* __restrict__ g2b, float* __restrict__ xf){
  int tid = threadIdx.x;
  int g = tid >> 3; int hd = tid & 7;
  int p = blockIdx.x*32 + g;
  int b = p >> 10; int n = p & 1023;
  __shared__ float ss[NNODE*NHEAD];          // 32 KB: s2 for this b
  __shared__ float outbuf[32][17];
  size_t bbase = (size_t)b*NNODE;
  for(int i=tid; i<NNODE*NHEAD; i+=256) ss[i] = s2[bbase*8 + i];
  __syncthreads();
  int o0 = off[n], o1 = off[n+1];
  float dn = d2[(bbase+n)*8+hd];
  float m = -1e30f, den = 0.f;
  for(int idx=o0; idx<o1; idx++){
    int pk = adjp[idx]; int s = pk >> 13;
    float lg = leaky(ss[s*8+hd] + dn, 0.2f);
    if(lg > m){ den *= expf(m - lg); m = lg; }
    den += expf(lg - m);
  }
  float inv = 1.f/(den + 1e-16f);
  float o_0=0.f, o_1=0.f;
  for(int idx=o0; idx<o1; idx++){
    int pk = adjp[idx]; int s = pk >> 13;
    float lg = leaky(ss[s*8+hd] + dn, 0.2f);
    float al = expf(lg - m)*inv;
    const float* hr = h2 + (bbase+s)*16 + hd*2;
    o_0 = fmaf(hr[0], al, o_0);
    o_1 = fmaf(hr[1], al, o_1);
  }
  outbuf[g][hd*2+0] = o_0;
  outbuf[g][hd*2+1] = o_1;
  __syncthreads();
  if(hd < 2){
    float acc = 0.f;
    #pragma unroll
    for(int k=0;k<8;k++) acc += outbuf[g][k*2+hd];
    float v = leaky(acc*0.125f + g2b[hd], 0.01f);
    xf[b*TWO_N + n*2 + hd] = v;
  }
}

// ---------------- cell GEMM (full K, gate-quadruple rows) + gates + cn + LN partials ----------------
// block q owns j rows {G*512 + 2q + r} for G=0..3, r=0..1  => can evaluate gates for u=2q,2q+1
__global__ __launch_bounds__(256) void k_cellgate(const float* __restrict__ xf,
    const float* __restrict__ hn, const float* __restrict__ Wih, const float* __restrict__ Whh,
    const float* __restrict__ bih, const float* __restrict__ bhh,
    float* __restrict__ cn, float* __restrict__ hraw, float* __restrict__ stats){
  __shared__ float xl[256*33];
  const int q = blockIdx.x;
  const int tid = threadIdx.x;
  const int jl = tid >> 5;         // 0..7: (G = jl>>1, r = jl&1)
  const int b  = tid & 31;
  const int j  = (jl>>1)*512 + q*2 + (jl&1);
  float a0=0,a1=0,a2=0,a3=0;
  for(int k0=0; k0<KCELL; k0+=256){
    if(k0 < TWO_N){
      for(int i=0;i<32;i++) xl[tid*33+i] = xf[i*TWO_N + k0 + tid];
    } else {
      for(int i=0;i<32;i++) xl[tid*33+i] = hn[i*HLL + (k0-TWO_N) + tid];
    }
    __syncthreads();
    const float* wrow = (k0 < TWO_N) ? (Wih + (size_t)j*TWO_N + k0)
                                     : (Whh + (size_t)j*HLL + (k0-TWO_N));
    #pragma unroll 4
    for(int kk=0; kk<256; kk+=8){
      float4 w0 = *reinterpret_cast<const float4*>(wrow + kk);
      float4 w1 = *reinterpret_cast<const float4*>(wrow + kk + 4);
      const float* xp = &xl[kk*33 + b];
      a0 = fmaf(w0.x, xp[0],   a0);
      a1 = fmaf(w0.y, xp[33],  a1);
      a2 = fmaf(w0.z, xp[66],  a2);
      a3 = fmaf(w0.w, xp[99],  a3);
      a0 = fmaf(w1.x, xp[132], a0);
      a1 = fmaf(w1.y, xp[165], a1);
      a2 = fmaf(w1.z, xp[198], a2);
      a3 = fmaf(w1.w, xp[231], a3);
    }
    __syncthreads();
  }
  float gv = (a0+a1)+(a2+a3) + bih[j] + bhh[j];
  // gate exchange via LDS (reuse xl)
  xl[jl*32 + b] = gv;
  __syncthreads();
  float hval = 0.f;
  if(jl < 2){
    int u = q*2 + jl;
    float gi = xl[(0+jl)*32 + b];
    float gf = xl[(2+jl)*32 + b];
    float gg = xl[(4+jl)*32 + b];
    float go = xl[(6+jl)*32 + b];
    float c = sigmoidf_(gf)*cn[b*HLL+u] + sigmoidf_(gi)*tanhf(gg);
    cn[b*HLL+u] = c;
    hval = sigmoidf_(go)*tanhf(c);
    hraw[b*HLL+u] = hval;
  }
  __syncthreads();
  if(jl < 2){
    xl[256 + jl*32 + b] = hval;          // [256..320)
    xl[384 + jl*32 + b] = hval*hval;     // [384..448)
  }
  __syncthreads();
  if(jl == 0){
    stats[(q*32 + b)*2 + 0] = xl[256 + b] + xl[288 + b];
    stats[(q*32 + b)*2 + 1] = xl[384 + b] + xl[416 + b];
  }
}

// ---------------- LN finalize + lin GEMM + softplus -> pred + fused next-step GAT1 prep ----------------
__global__ __launch_bounds__(256) void k_linln(const float* __restrict__ hraw,
    const float* __restrict__ stats, const float* __restrict__ lng, const float* __restrict__ lnb,
    float* __restrict__ hn,
    const float* __restrict__ W, const float* __restrict__ bias,
    const float* __restrict__ runoff, float* __restrict__ pred,
    float* __restrict__ h1, float* __restrict__ s1, float* __restrict__ d1,
    const float* __restrict__ g1W, const float* __restrict__ g1as, const float* __restrict__ g1ad,
    int t){
  __shared__ float hl[256*33];
  __shared__ float red1[256], red2[256];
  __shared__ float musd[32], rstds[32];
  const int q = blockIdx.x;
  const int tid = threadIdx.x;
  // --- reduce LN stats: 8 threads per batch ---
  {
    int b8 = tid >> 3, l8 = tid & 7;
    float s = 0.f, s2 = 0.f;
    for(int qq = l8*32; qq < l8*32+32; qq++){
      s  += stats[(qq*32 + b8)*2 + 0];
      s2 += stats[(qq*32 + b8)*2 + 1];
    }
    red1[tid] = s; red2[tid] = s2;
    __syncthreads();
    if(l8 < 4){ red1[tid] += red1[tid+4]; red2[tid] += red2[tid+4]; }
    __syncthreads();
    if(l8 < 2){ red1[tid] += red1[tid+2]; red2[tid] += red2[tid+2]; }
    __syncthreads();
    if(l8 == 0){
      float S = red1[tid] + red1[tid+1];
      float S2 = red2[tid] + red2[tid+1];
      float mu = S * (1.f/HLL);
      float var = S2 * (1.f/HLL) - mu*mu;
      musd[b8] = mu;
      rstds[b8] = rsqrtf(var + 1e-5f);
    }
    __syncthreads();
  }
  // --- write this block's 64-element slice of normalized hn (for next-step cell GEMM) ---
  if(tid < 64){
    int e = q*64 + tid; int b = e >> 9; int u = e & 511;
    hn[e] = (hraw[e] - musd[b])*rstds[b]*lng[u] + lnb[u];
  }
  // --- lin GEMM with LN applied inline at staging ---
  int jl = tid >> 5; int b = tid & 31;
  int j = q*8 + jl;
  float a0=0.f,a1=0.f,a2=0.f,a3=0.f;
  for(int k0=0; k0<HLL; k0+=256){
    float lg_ = lng[k0+tid], lb_ = lnb[k0+tid];
    __syncthreads();
    for(int i=0;i<32;i++)
      hl[tid*33+i] = (hraw[i*HLL + k0 + tid] - musd[i])*rstds[i]*lg_ + lb_;
    __syncthreads();
    const float* wrow = W + (size_t)j*HLL + k0;
    #pragma unroll 4
    for(int kk=0; kk<256; kk+=8){
      float4 w0 = *reinterpret_cast<const float4*>(wrow + kk);
      float4 w1 = *reinterpret_cast<const float4*>(wrow + kk + 4);
      const float* xp = &hl[kk*33 + b];
      a0 = fmaf(w0.x, xp[0],   a0);
      a1 = fmaf(w0.y, xp[33],  a1);
      a2 = fmaf(w0.z, xp[66],  a2);
      a3 = fmaf(w0.w, xp[99],  a3);
      a0 = fmaf(w1.x, xp[132], a0);
      a1 = fmaf(w1.y, xp[165], a1);
      a2 = fmaf(w1.z, xp[198], a2);
      a3 = fmaf(w1.w, xp[231], a3);
    }
  }
  float val = (a0+a1)+(a2+a3) + bias[j];
  float sp = fmaxf(val, 0.f) + log1pf(expf(-fabsf(val)));   // softplus, stable
  pred[((size_t)b*TT + t)*TWO_N + j] = sp;
  if(t+1 < TT){
    float partner = __shfl_xor(sp, 32);   // jl parity swap within wave64, same b
    if((jl & 1) == 0){
      int n = j >> 1;
      float x2 = runoff[(size_t)(t+1)*BB*NNODE + b*NNODE + n];
      float hv2[24];
      size_t base = (size_t)b*NNODE + n;
      #pragma unroll
      for(int o=0;o<24;o++){
        hv2[o] = sp*g1W[o] + partner*g1W[24+o] + x2*g1W[48+o];
        h1[base*24+o] = hv2[o];
      }
      #pragma unroll
      for(int hd=0; hd<NHEAD; hd++){
        float s=0.f, d=0.f;
        #pragma unroll
        for(int c2=0;c2<3;c2++){
          float v2 = hv2[hd*3+c2];
          s = fmaf(v2, g1as[hd*3+c2], s);
          d = fmaf(v2, g1ad[hd*3+c2], d);
        }
        s1[base*8+hd] = s; d1[base*8+hd] = d;
      }
    }
  }
}

// ---------------- init hn/cn to zero ----------------
__global__ __launch_bounds__(512) void k_init(float* __restrict__ hn, float* __restrict__ cn){
  int idx = blockIdx.x*512 + threadIdx.x;   // 32768
  if(idx < BB*HLL) hn[idx] = 0.f;
  else cn[idx - BB*HLL] = 0.f;
}

extern "C" void kernel_launch(void* const* d_in, const int* in_sizes, int n_in,
                              void* d_out, int out_size, void* d_ws, size_t ws_size,
                              hipStream_t stream){
  const float* rainfall  = (const float*)d_in[0];
  const float* inflow    = (const float*)d_in[1];
  const int*   edge_index= (const int*)  d_in[2];
  const float* lstm_Wih  = (const float*)d_in[3];
  const float* lstm_Whh  = (const float*)d_in[4];
  const float* lstm_bih  = (const float*)d_in[5];
  const float* lstm_bhh  = (const float*)d_in[6];
  const float* fc_W      = (const float*)d_in[7];
  const float* fc_b      = (const float*)d_in[8];
  const float* g1_W      = (const float*)d_in[9];
  const float* g1_as     = (const float*)d_in[10];
  const float* g1_ad     = (const float*)d_in[11];
  const float* g1_b      = (const float*)d_in[12];
  const float* g2_W      = (const float*)d_in[13];
  const float* g2_as     = (const float*)d_in[14];
  const float* g2_ad     = (const float*)d_in[15];
  const float* g2_b      = (const float*)d_in[16];
  const float* cell_Wih  = (const float*)d_in[17];
  const float* cell_Whh  = (const float*)d_in[18];
  const float* cell_bih  = (const float*)d_in[19];
  const float* cell_bhh  = (const float*)d_in[20];
  const float* ln_g      = (const float*)d_in[21];
  const float* ln_b      = (const float*)d_in[22];
  const float* lin_W     = (const float*)d_in[23];
  const float* lin_b     = (const float*)d_in[24];

  float* out  = (float*)d_out;
  float* pred = out;                       // (B,T,2N) = 4194304
  float* lat  = out + (size_t)4194304;     // (B,T,N,1) = 2097152
  float* att  = out + (size_t)6291456;     // (T,B,5120,8)

  float* ws = (float*)d_ws;
  float* hs     = ws;                        // 131072
  float* runoff = hs + 131072;               // 2097152
  float* h1     = runoff + 2097152;          // 786432
  float* s1     = h1 + 786432;               // 262144
  float* d1     = s1 + 262144;               // 262144
  float* h2     = d1 + 262144;               // 524288
  float* s2     = h2 + 524288;               // 262144
  float* d2     = s2 + 262144;               // 262144
  float* xfb    = d2 + 262144;               // 65536
  float* hraw   = xfb + 65536;               // 16384
  float* stats  = hraw + 16384;              // 16384
  float* hn     = stats + 16384;             // 16384
  float* cn     = hn + 16384;                // 16384
  int*   off    = (int*)(cn + 16384);        // 1025 (pad 1032)
  int*   adjp   = off + 1032;                // 5120
  if(ws_size < 18898976ull) return;          // diagnostic: zero output

  k_init<<<64, 512, 0, stream>>>(hn, cn);
  k_csr_off<<<1, 1024, 0, stream>>>(edge_index, off);
  k_csr_fill<<<4, 1024, 0, stream>>>(edge_index, off, adjp);
  k_lstm<<<BB, 256, 0, stream>>>(rainfall, lstm_Wih, lstm_Whh, lstm_bih, lstm_bhh, hs);
  k_runoff<<<TT*BB*4, 256, 0, stream>>>(hs, fc_W, fc_b, inflow, runoff, lat);
  k_prep0<<<128, 256, 0, stream>>>(runoff, g1_W, g1_as, g1_ad, h1, s1, d1);

  for(int t=0; t<TT; t++){
    k_gat1f<<<1024, 256, 0, stream>>>(adjp, off, h1, s1, d1,
        g1_b, g2_W, g2_as, g2_ad, h2, s2, d2, att, t);
    k_gat2f<<<1024, 256, 0, stream>>>(adjp, off, h2, s2, d2, g2_b, xfb);
    k_cellgate<<<256, 256, 0, stream>>>(xfb, hn, cell_Wih, cell_Whh,
        cell_bih, cell_bhh, cn, hraw, stats);
    k_linln<<<256, 256, 0, stream>>>(hraw, stats, ln_g, ln_b, hn,
        lin_W, lin_b, runoff, pred, h1, s1, d1, g1_W, g1_as, g1_ad, t);
  }
}

// Round 15
// 5837.248 us; speedup vs baseline: 3.6365x; 1.0901x over previous
//
#include <hip/hip_runtime.h>
#include <hip/hip_bf16.h>

#define BB 32
#define TT 64
#define NNODE 1024
#define EE 4096
#define NEDGE 5120        // EE + NNODE self loops
#define NHEAD 8
#define HLL 512
#define HRR 64
#define TWO_N 2048
#define KCELL 2560

__device__ __forceinline__ float sigmoidf_(float x){ return 1.f/(1.f+expf(-x)); }
__device__ __forceinline__ float leaky(float x, float s){ return x>0.f? x : s*x; }

// ---------------- CSR by dst (deterministic), packed (src<<13 | eid) ----------------
__global__ __launch_bounds__(1024) void k_csr_off(const int* __restrict__ ei, int* __restrict__ off){
  __shared__ int deg[NNODE];
  __shared__ int scn[NNODE];
  int tid = threadIdx.x;
  deg[tid] = 1;  // self loop
  __syncthreads();
  for(int e=tid; e<EE; e+=1024) atomicAdd(&deg[ei[EE+e]], 1);
  __syncthreads();
  scn[tid] = deg[tid];
  __syncthreads();
  for(int ofs=1; ofs<1024; ofs<<=1){
    int add = (tid>=ofs)? scn[tid-ofs] : 0;
    __syncthreads();
    scn[tid] += add;
    __syncthreads();
  }
  off[tid+1] = scn[tid];
  if(tid==0) off[0] = 0;
}

__global__ __launch_bounds__(1024) void k_csr_fill(const int* __restrict__ ei,
    const int* __restrict__ off, int* __restrict__ adjp){
  __shared__ int dstb[EE];
  int tid = threadIdx.x;
  for(int e=tid; e<EE; e+=1024) dstb[e] = ei[EE+e];
  __syncthreads();
  int e = blockIdx.x*1024 + tid;
  int myd = dstb[e];
  int rank = 0;
  for(int ep=0; ep<e; ep++) rank += (dstb[ep]==myd) ? 1 : 0;
  adjp[off[myd]+rank] = (ei[e] << 13) | e;                          // real edge
  if(blockIdx.x==0) adjp[off[tid+1]-1] = (tid << 13) | (EE + tid);  // self loop last
}

// ---------------- LSTM over T steps, one block per batch ----------------
__global__ __launch_bounds__(256) void k_lstm(
    const float* __restrict__ rain, const float* __restrict__ Wih,
    const float* __restrict__ Whh, const float* __restrict__ bih,
    const float* __restrict__ bhh, float* __restrict__ hs){
  int b = blockIdx.x;
  int j = threadIdx.x;
  __shared__ float h_lds[HRR];
  __shared__ float g_lds[4*HRR];
  float wh[HRR];
  #pragma unroll
  for(int k=0;k<HRR;k++) wh[k] = Whh[j*HRR+k];
  float wi = Wih[j];
  float bias = bih[j] + bhh[j];
  float c = 0.f;
  if(j < HRR) h_lds[j] = 0.f;
  __syncthreads();
  for(int t=0;t<TT;t++){
    float x = rain[b*TT+t];
    float g = fmaf(wi, x, bias);
    #pragma unroll
    for(int k=0;k<HRR;k++) g = fmaf(wh[k], h_lds[k], g);
    g_lds[j] = g;
    __syncthreads();
    if(j < HRR){
      c = sigmoidf_(g_lds[HRR+j])*c + sigmoidf_(g_lds[j])*tanhf(g_lds[2*HRR+j]);
      float h = sigmoidf_(g_lds[3*HRR+j])*tanhf(c);
      h_lds[j] = h;
      hs[(t*BB+b)*HRR + j] = h;
    }
    __syncthreads();
  }
}

// ---------------- runoff = leaky(hs @ fcW^T + fcb), + inflow at node 753 ----------------
__global__ __launch_bounds__(256) void k_runoff(
    const float* __restrict__ hs, const float* __restrict__ fcW,
    const float* __restrict__ fcb, const float* __restrict__ inflow,
    float* __restrict__ runoff, float* __restrict__ lat){
  int p = blockIdx.x;
  int q = p & 3; int tb = p >> 2; int t = tb >> 5; int b = tb & 31;
  int n = q*256 + threadIdx.x;
  __shared__ float hrow[HRR];
  if(threadIdx.x < HRR) hrow[threadIdx.x] = hs[(t*BB+b)*HRR + threadIdx.x];
  __syncthreads();
  const float* wrow = fcW + n*HRR;
  float a0=0,a1=0,a2=0,a3=0;
  #pragma unroll
  for(int k=0;k<HRR;k+=4){
    float4 w = *reinterpret_cast<const float4*>(wrow + k);
    a0 = fmaf(w.x, hrow[k+0], a0);
    a1 = fmaf(w.y, hrow[k+1], a1);
    a2 = fmaf(w.z, hrow[k+2], a2);
    a3 = fmaf(w.w, hrow[k+3], a3);
  }
  float acc = (a0+a1)+(a2+a3) + fcb[n];
  float r = leaky(acc, 0.01f);
  if(n == 753) r += inflow[b*TT + t];
  runoff[(t*BB+b)*NNODE + n] = r;
  lat[(size_t)(b*TT+t)*NNODE + n] = r;
}

// ---------------- GAT1 node prep for t=0 ----------------
__global__ __launch_bounds__(256) void k_prep0(const float* __restrict__ runoff,
    const float* __restrict__ g1W, const float* __restrict__ g1as, const float* __restrict__ g1ad,
    float* __restrict__ h1, float* __restrict__ s1, float* __restrict__ d1){
  int idx = blockIdx.x*256 + threadIdx.x;    // 32768 = B*N
  int b = idx >> 10; int n = idx & 1023;
  float x2 = runoff[b*NNODE + n];            // t=0
  float hv[24];
  size_t base = (size_t)b*NNODE + n;
  #pragma unroll
  for(int o=0;o<24;o++){
    hv[o] = x2*g1W[48+o];
    h1[base*24+o] = hv[o];
  }
  #pragma unroll
  for(int hd=0; hd<NHEAD; hd++){
    float s=0.f, d=0.f;
    #pragma unroll
    for(int c=0;c<3;c++){
      float v = hv[hd*3+c];
      s = fmaf(v, g1as[hd*3+c], s);
      d = fmaf(v, g1ad[hd*3+c], d);
    }
    s1[base*8+hd] = s; d1[base*8+hd] = d;
  }
}

// ---------------- GAT1 edge pass (512 thr, 64 nodes/block) + GAT2 prep ----------------
__global__ __launch_bounds__(512) void k_gat1f(
    const int* __restrict__ adjp, const int* __restrict__ off,
    const float* __restrict__ h1, const float* __restrict__ s1, const float* __restrict__ d1,
    const float* __restrict__ g1b, const float* __restrict__ g2W,
    const float* __restrict__ g2as, const float* __restrict__ g2ad,
    float* __restrict__ h2, float* __restrict__ s2, float* __restrict__ d2,
    float* __restrict__ att, int t){
  int tid = threadIdx.x;
  int g = tid >> 3; int hd = tid & 7;
  int p = blockIdx.x*64 + g;                 // (b,n); all groups in a block share b
  int b = p >> 10; int n = p & 1023;
  __shared__ float ss[NNODE*NHEAD];          // 32 KB: s1 for this b
  __shared__ float x1buf[64][25];
  size_t bbase = (size_t)b*NNODE;
  for(int i=tid; i<NNODE*NHEAD; i+=512) ss[i] = s1[bbase*8 + i];
  __syncthreads();
  int o0 = off[n], o1 = off[n+1];
  float dn = d1[(bbase+n)*8+hd];
  float m = -1e30f, den = 0.f;
  for(int idx=o0; idx<o1; idx++){
    int pk = adjp[idx]; int s = pk >> 13;
    float lg = leaky(ss[s*8+hd] + dn, 0.2f);
    if(lg > m){ den *= expf(m - lg); m = lg; }
    den += expf(lg - m);
  }
  float inv = 1.f/(den + 1e-16f);
  float o_0=0.f, o_1=0.f, o_2=0.f;
  for(int idx=o0; idx<o1; idx++){
    int pk = adjp[idx]; int s = pk >> 13; int eid = pk & 8191;
    float lg = leaky(ss[s*8+hd] + dn, 0.2f);
    float al = expf(lg - m)*inv;
    att[((size_t)(t*BB+b)*NEDGE + eid)*NHEAD + hd] = al;
    const float* hr = h1 + (bbase+s)*24 + hd*3;
    o_0 = fmaf(hr[0], al, o_0);
    o_1 = fmaf(hr[1], al, o_1);
    o_2 = fmaf(hr[2], al, o_2);
  }
  x1buf[g][hd*3+0] = leaky(o_0 + g1b[hd*3+0], 0.01f);
  x1buf[g][hd*3+1] = leaky(o_1 + g1b[hd*3+1], 0.01f);
  x1buf[g][hd*3+2] = leaky(o_2 + g1b[hd*3+2], 0.01f);
  __syncthreads();
  // GAT2 node prep: h2 (16), s2/d2 (8)
  float h2v0=0.f, h2v1=0.f;
  int oA = hd*2, oB = hd*2+1;
  #pragma unroll
  for(int k=0;k<24;k++){
    float xv = x1buf[g][k];
    h2v0 = fmaf(xv, g2W[k*16+oA], h2v0);
    h2v1 = fmaf(xv, g2W[k*16+oB], h2v1);
  }
  h2[(bbase+n)*16+oA] = h2v0;
  h2[(bbase+n)*16+oB] = h2v1;
  s2[(bbase+n)*8+hd] = h2v0*g2as[oA] + h2v1*g2as[oB];
  d2[(bbase+n)*8+hd] = h2v0*g2ad[oA] + h2v1*g2ad[oB];
}

// ---------------- GAT2 edge pass (512 thr, 64 nodes/block) -> xf ----------------
__global__ __launch_bounds__(512) void k_gat2f(
    const int* __restrict__ adjp, const int* __restrict__ off,
    const float* __restrict__ h2, const float* __restrict__ s2, const float* __restrict__ d2,
    const float* __restrict__ g2b, float* __restrict__ xf){
  int tid = threadIdx.x;
  int g = tid >> 3; int hd = tid & 7;
  int p = blockIdx.x*64 + g;
  int b = p >> 10; int n = p & 1023;
  __shared__ float ss[NNODE*NHEAD];          // 32 KB: s2 for this b
  __shared__ float outbuf[64][17];
  size_t bbase = (size_t)b*NNODE;
  for(int i=tid; i<NNODE*NHEAD; i+=512) ss[i] = s2[bbase*8 + i];
  __syncthreads();
  int o0 = off[n], o1 = off[n+1];
  float dn = d2[(bbase+n)*8+hd];
  float m = -1e30f, den = 0.f;
  for(int idx=o0; idx<o1; idx++){
    int pk = adjp[idx]; int s = pk >> 13;
    float lg = leaky(ss[s*8+hd] + dn, 0.2f);
    if(lg > m){ den *= expf(m - lg); m = lg; }
    den += expf(lg - m);
  }
  float inv = 1.f/(den + 1e-16f);
  float o_0=0.f, o_1=0.f;
  for(int idx=o0; idx<o1; idx++){
    int pk = adjp[idx]; int s = pk >> 13;
    float lg = leaky(ss[s*8+hd] + dn, 0.2f);
    float al = expf(lg - m)*inv;
    const float* hr = h2 + (bbase+s)*16 + hd*2;
    o_0 = fmaf(hr[0], al, o_0);
    o_1 = fmaf(hr[1], al, o_1);
  }
  outbuf[g][hd*2+0] = o_0;
  outbuf[g][hd*2+1] = o_1;
  __syncthreads();
  if(hd < 2){
    float acc = 0.f;
    #pragma unroll
    for(int k=0;k<8;k++) acc += outbuf[g][k*2+hd];
    float v = leaky(acc*0.125f + g2b[hd], 0.01f);
    xf[b*TWO_N + n*2 + hd] = v;
  }
}

// ---------------- cell GEMM split-K2, 2 j-rows per thread (256 blocks) ----------------
__global__ __launch_bounds__(256) void k_cell_gemm(const float* __restrict__ xf,
    const float* __restrict__ hn, const float* __restrict__ Wih, const float* __restrict__ Whh,
    float* __restrict__ g0, float* __restrict__ g1){
  __shared__ float xl[256*33];
  int bid = blockIdx.x;
  int half = bid >> 7; int jb = bid & 127;
  int tid = threadIdx.x;
  int jl = tid >> 5; int b = tid & 31;
  int j0 = jb*16 + jl*2;
  float a00=0,a01=0,a02=0,a03=0, a10=0,a11=0,a12=0,a13=0;
  int kbeg = half*1280, kend = kbeg + 1280;
  for(int k0=kbeg; k0<kend; k0+=256){
    if(k0 < TWO_N){
      for(int i=0;i<32;i++) xl[tid*33+i] = xf[i*TWO_N + k0 + tid];
    } else {
      for(int i=0;i<32;i++) xl[tid*33+i] = hn[i*HLL + (k0-TWO_N) + tid];
    }
    __syncthreads();
    const float* wr0;
    const float* wr1;
    if(k0 < TWO_N){
      wr0 = Wih + (size_t)j0*TWO_N + k0;
      wr1 = Wih + (size_t)(j0+1)*TWO_N + k0;
    } else {
      wr0 = Whh + (size_t)j0*HLL + (k0-TWO_N);
      wr1 = Whh + (size_t)(j0+1)*HLL + (k0-TWO_N);
    }
    #pragma unroll 4
    for(int kk=0; kk<256; kk+=8){
      float4 w00 = *reinterpret_cast<const float4*>(wr0 + kk);
      float4 w01 = *reinterpret_cast<const float4*>(wr0 + kk + 4);
      float4 w10 = *reinterpret_cast<const float4*>(wr1 + kk);
      float4 w11 = *reinterpret_cast<const float4*>(wr1 + kk + 4);
      const float* xp = &xl[kk*33 + b];
      float xv0=xp[0], xv1=xp[33], xv2=xp[66], xv3=xp[99];
      float xv4=xp[132], xv5=xp[165], xv6=xp[198], xv7=xp[231];
      a00 = fmaf(w00.x, xv0, a00);  a10 = fmaf(w10.x, xv0, a10);
      a01 = fmaf(w00.y, xv1, a01);  a11 = fmaf(w10.y, xv1, a11);
      a02 = fmaf(w00.z, xv2, a02);  a12 = fmaf(w10.z, xv2, a12);
      a03 = fmaf(w00.w, xv3, a03);  a13 = fmaf(w10.w, xv3, a13);
      a00 = fmaf(w01.x, xv4, a00);  a10 = fmaf(w11.x, xv4, a10);
      a01 = fmaf(w01.y, xv5, a01);  a11 = fmaf(w11.y, xv5, a11);
      a02 = fmaf(w01.z, xv6, a02);  a12 = fmaf(w11.z, xv6, a12);
      a03 = fmaf(w01.w, xv7, a03);  a13 = fmaf(w11.w, xv7, a13);
    }
    __syncthreads();
  }
  float* dst = half ? g1 : g0;
  dst[b*TWO_N + j0]     = (a00+a01)+(a02+a03);
  dst[b*TWO_N + j0 + 1] = (a10+a11)+(a12+a13);
}

// ---------------- gates (sum partials + biases) + LayerNorm ----------------
__global__ __launch_bounds__(512) void k_cell_gate(const float* __restrict__ g0,
    const float* __restrict__ g1,
    const float* __restrict__ bih, const float* __restrict__ bhh,
    float* __restrict__ cn, float* __restrict__ hn,
    const float* __restrict__ lng, const float* __restrict__ lnb){
  int b = blockIdx.x; int u = threadIdx.x;   // 512
  const float* r0 = g0 + b*TWO_N;
  const float* r1 = g1 + b*TWO_N;
  float gi = r0[u]       + r1[u]       + bih[u]       + bhh[u];
  float gf = r0[HLL+u]   + r1[HLL+u]   + bih[HLL+u]   + bhh[HLL+u];
  float gg = r0[2*HLL+u] + r1[2*HLL+u] + bih[2*HLL+u] + bhh[2*HLL+u];
  float go = r0[3*HLL+u] + r1[3*HLL+u] + bih[3*HLL+u] + bhh[3*HLL+u];
  float c = sigmoidf_(gf)*cn[b*HLL+u] + sigmoidf_(gi)*tanhf(gg);
  cn[b*HLL+u] = c;
  float h = sigmoidf_(go)*tanhf(c);
  __shared__ float red[HLL];
  __shared__ float red2[HLL];
  red[u] = h; red2[u] = h*h;
  __syncthreads();
  for(int s=256; s>0; s>>=1){
    if(u < s){ red[u] += red[u+s]; red2[u] += red2[u+s]; }
    __syncthreads();
  }
  float mu = red[0] * (1.f/HLL);
  float var = red2[0] * (1.f/HLL) - mu*mu;
  float rstd = rsqrtf(var + 1e-5f);
  hn[b*HLL+u] = (h-mu)*rstd*lng[u] + lnb[u];
}

// ---------------- lin GEMM + softplus -> pred(t) + fused next-step GAT1 prep ----------------
__global__ __launch_bounds__(256) void k_lin(const float* __restrict__ hn,
    const float* __restrict__ W, const float* __restrict__ bias,
    const float* __restrict__ runoff, float* __restrict__ pred,
    float* __restrict__ h1, float* __restrict__ s1, float* __restrict__ d1,
    const float* __restrict__ g1W, const float* __restrict__ g1as, const float* __restrict__ g1ad,
    int t){
  __shared__ float hl[256*33];
  int tid = threadIdx.x;
  int jl = tid >> 5; int b = tid & 31;
  int j = blockIdx.x*8 + jl;
  float a0=0,a1=0,a2=0,a3=0;
  for(int k0=0; k0<HLL; k0+=256){
    for(int i=0;i<32;i++) hl[tid*33+i] = hn[i*HLL + k0 + tid];
    __syncthreads();
    const float* wrow = W + (size_t)j*HLL + k0;
    #pragma unroll 4
    for(int kk=0; kk<256; kk+=8){
      float4 w0 = *reinterpret_cast<const float4*>(wrow + kk);
      float4 w1 = *reinterpret_cast<const float4*>(wrow + kk + 4);
      const float* xp = &hl[kk*33 + b];
      a0 = fmaf(w0.x, xp[0],   a0);
      a1 = fmaf(w0.y, xp[33],  a1);
      a2 = fmaf(w0.z, xp[66],  a2);
      a3 = fmaf(w0.w, xp[99],  a3);
      a0 = fmaf(w1.x, xp[132], a0);
      a1 = fmaf(w1.y, xp[165], a1);
      a2 = fmaf(w1.z, xp[198], a2);
      a3 = fmaf(w1.w, xp[231], a3);
    }
    __syncthreads();
  }
  float val = (a0+a1)+(a2+a3) + bias[j];
  float sp = fmaxf(val, 0.f) + log1pf(expf(-fabsf(val)));   // softplus, stable
  pred[((size_t)b*TT + t)*TWO_N + j] = sp;
  if(t+1 < TT){
    float partner = __shfl_xor(sp, 32);   // pairs jl<->jl^1 within wave64, same b
    if((jl & 1) == 0){
      int n = j >> 1;
      float x2 = runoff[(size_t)(t+1)*BB*NNODE + b*NNODE + n];
      float hv[24];
      size_t base = (size_t)b*NNODE + n;
      #pragma unroll
      for(int o=0;o<24;o++){
        hv[o] = sp*g1W[o] + partner*g1W[24+o] + x2*g1W[48+o];
        h1[base*24+o] = hv[o];
      }
      #pragma unroll
      for(int hd=0; hd<NHEAD; hd++){
        float s=0.f, d=0.f;
        #pragma unroll
        for(int c=0;c<3;c++){
          float v = hv[hd*3+c];
          s = fmaf(v, g1as[hd*3+c], s);
          d = fmaf(v, g1ad[hd*3+c], d);
        }
        s1[base*8+hd] = s; d1[base*8+hd] = d;
      }
    }
  }
}

// ---------------- init hn/cn to zero ----------------
__global__ __launch_bounds__(512) void k_init(float* __restrict__ hn, float* __restrict__ cn){
  int idx = blockIdx.x*512 + threadIdx.x;   // 32768
  if(idx < BB*HLL) hn[idx] = 0.f;
  else cn[idx - BB*HLL] = 0.f;
}

extern "C" void kernel_launch(void* const* d_in, const int* in_sizes, int n_in,
                              void* d_out, int out_size, void* d_ws, size_t ws_size,
                              hipStream_t stream){
  const float* rainfall  = (const float*)d_in[0];
  const float* inflow    = (const float*)d_in[1];
  const int*   edge_index= (const int*)  d_in[2];
  const float* lstm_Wih  = (const float*)d_in[3];
  const float* lstm_Whh  = (const float*)d_in[4];
  const float* lstm_bih  = (const float*)d_in[5];
  const float* lstm_bhh  = (const float*)d_in[6];
  const float* fc_W      = (const float*)d_in[7];
  const float* fc_b      = (const float*)d_in[8];
  const float* g1_W      = (const float*)d_in[9];
  const float* g1_as     = (const float*)d_in[10];
  const float* g1_ad     = (const float*)d_in[11];
  const float* g1_b      = (const float*)d_in[12];
  const float* g2_W      = (const float*)d_in[13];
  const float* g2_as     = (const float*)d_in[14];
  const float* g2_ad     = (const float*)d_in[15];
  const float* g2_b      = (const float*)d_in[16];
  const float* cell_Wih  = (const float*)d_in[17];
  const float* cell_Whh  = (const float*)d_in[18];
  const float* cell_bih  = (const float*)d_in[19];
  const float* cell_bhh  = (const float*)d_in[20];
  const float* ln_g      = (const float*)d_in[21];
  const float* ln_b      = (const float*)d_in[22];
  const float* lin_W     = (const float*)d_in[23];
  const float* lin_b     = (const float*)d_in[24];

  float* out  = (float*)d_out;
  float* pred = out;                       // (B,T,2N) = 4194304
  float* lat  = out + (size_t)4194304;     // (B,T,N,1) = 2097152
  float* att  = out + (size_t)6291456;     // (T,B,5120,8)

  float* ws = (float*)d_ws;
  float* hs     = ws;                        // 131072
  float* runoff = hs + 131072;               // 2097152
  float* h1     = runoff + 2097152;          // 786432
  float* s1     = h1 + 786432;               // 262144
  float* d1     = s1 + 262144;               // 262144
  float* h2     = d1 + 262144;               // 524288
  float* s2     = h2 + 524288;               // 262144
  float* d2     = s2 + 262144;               // 262144
  float* xfb    = d2 + 262144;               // 65536
  float* g0buf  = xfb + 65536;               // 65536
  float* g1buf  = g0buf + 65536;             // 65536
  float* hn     = g1buf + 65536;             // 16384
  float* cn     = hn + 16384;                // 16384
  int*   off    = (int*)(cn + 16384);        // 1025 (pad 1032)
  int*   adjp   = off + 1032;                // 5120
  if(ws_size < 19292192ull) return;          // diagnostic: zero output

  k_init<<<64, 512, 0, stream>>>(hn, cn);
  k_csr_off<<<1, 1024, 0, stream>>>(edge_index, off);
  k_csr_fill<<<4, 1024, 0, stream>>>(edge_index, off, adjp);
  k_lstm<<<BB, 256, 0, stream>>>(rainfall, lstm_Wih, lstm_Whh, lstm_bih, lstm_bhh, hs);
  k_runoff<<<TT*BB*4, 256, 0, stream>>>(hs, fc_W, fc_b, inflow, runoff, lat);
  k_prep0<<<128, 256, 0, stream>>>(runoff, g1_W, g1_as, g1_ad, h1, s1, d1);

  for(int t=0; t<TT; t++){
    k_gat1f<<<512, 512, 0, stream>>>(adjp, off, h1, s1, d1,
        g1_b, g2_W, g2_as, g2_ad, h2, s2, d2, att, t);
    k_gat2f<<<512, 512, 0, stream>>>(adjp, off, h2, s2, d2, g2_b, xfb);
    k_cell_gemm<<<256, 256, 0, stream>>>(xfb, hn, cell_Wih, cell_Whh, g0buf, g1buf);
    k_cell_gate<<<BB, 512, 0, stream>>>(g0buf, g1buf, cell_bih, cell_bhh, cn, hn, ln_g, ln_b);
    k_lin<<<256, 256, 0, stream>>>(hn, lin_W, lin_b, runoff, pred,
        h1, s1, d1, g1_W, g1_as, g1_ad, t);
  }
}